// Round 1
// baseline (2818.731 us; speedup 1.0000x reference)
//
#include <hip/hip_runtime.h>
#include <math.h>

// ---------------- helpers ----------------

__device__ inline unsigned fkey(float x) {
  // monotone float -> uint key for atomicMax on floats
  int i = __float_as_int(x);
  return (i >= 0) ? ((unsigned)i | 0x80000000u) : ~((unsigned)i);
}
__device__ inline float unfkey(unsigned k) {
  int i = (k & 0x80000000u) ? (int)(k & 0x7fffffffu) : ~(int)k;
  return __int_as_float(i);
}

// ---------------- GEMM (f32, 64x64 tile, 4x4/thread) ----------------
// A: [M,K] row-major, B: [K,N] row-major, C: [M,N]. N%64==0, K%16==0, M guarded.
__global__ __launch_bounds__(256) void gemm_f32(const float* __restrict__ A,
                                                const float* __restrict__ B,
                                                float* __restrict__ C,
                                                int M, int N, int K) {
  __shared__ float As[16][64];  // transposed: As[k][m]
  __shared__ float Bs[16][64];  // Bs[k][n]
  const int tid = threadIdx.x;
  const int tx = tid & 15, ty = tid >> 4;
  const int nBase = blockIdx.x * 64;
  const int mBase = blockIdx.y * 64;
  const int aRow = tid >> 2;          // 0..63
  const int aK   = (tid & 3) << 2;    // 0,4,8,12
  const int bC   = tid & 63;
  const int bR0  = tid >> 6;          // 0..3
  float acc[4][4] = {};
  for (int k0 = 0; k0 < K; k0 += 16) {
    float4 av = make_float4(0.f, 0.f, 0.f, 0.f);
    int gr = mBase + aRow;
    if (gr < M) av = *(const float4*)&A[(size_t)gr * K + k0 + aK];
    As[aK + 0][aRow] = av.x;
    As[aK + 1][aRow] = av.y;
    As[aK + 2][aRow] = av.z;
    As[aK + 3][aRow] = av.w;
#pragma unroll
    for (int i = 0; i < 4; ++i) {
      int r = bR0 + i * 4;
      Bs[r][bC] = B[(size_t)(k0 + r) * N + nBase + bC];
    }
    __syncthreads();
#pragma unroll
    for (int k = 0; k < 16; ++k) {
      float4 a = *(const float4*)&As[k][ty * 4];
      float4 b = *(const float4*)&Bs[k][tx * 4];
      float ar[4] = {a.x, a.y, a.z, a.w};
      float br[4] = {b.x, b.y, b.z, b.w};
#pragma unroll
      for (int i = 0; i < 4; ++i)
#pragma unroll
        for (int j = 0; j < 4; ++j) acc[i][j] = fmaf(ar[i], br[j], acc[i][j]);
    }
    __syncthreads();
  }
#pragma unroll
  for (int i = 0; i < 4; ++i) {
    int gr = mBase + ty * 4 + i;
    if (gr < M) {
      float4 v = make_float4(acc[i][0], acc[i][1], acc[i][2], acc[i][3]);
      *(float4*)&C[(size_t)gr * N + nBase + tx * 4] = v;
    }
  }
}

// ---------------- alpha_s / alpha_d: one wave per (node, head), C=128 ----------------
__global__ void calc_alpha(const float* __restrict__ H, const float* __restrict__ a_src,
                           const float* __restrict__ a_dst, float* __restrict__ as_out,
                           float* __restrict__ ad_out, int N, int Hh) {
  int wid = (int)((blockIdx.x * blockDim.x + threadIdx.x) >> 6);
  int lane = threadIdx.x & 63;
  if (wid >= N * Hh) return;
  int n = wid / Hh, h = wid % Hh;
  const float* hv = H + (size_t)n * (Hh * 128) + h * 128;
  const float* sv = a_src + h * 128;
  const float* dv = a_dst + h * 128;
  float s = hv[lane] * sv[lane] + hv[lane + 64] * sv[lane + 64];
  float d = hv[lane] * dv[lane] + hv[lane + 64] * dv[lane + 64];
#pragma unroll
  for (int o = 32; o; o >>= 1) {
    s += __shfl_down(s, o);
    d += __shfl_down(d, o);
  }
  if (lane == 0) {
    as_out[wid] = s;
    ad_out[wid] = d;
  }
}

// ---------------- edge kernels ----------------
__device__ inline void edge_nodes(const int* __restrict__ ei, int E0, int e, int& s, int& d) {
  if (e < E0) { s = ei[e]; d = ei[E0 + e]; }
  else        { s = e - E0; d = e - E0; }   // self-loop
}

__global__ void edge_max(const int* __restrict__ ei, int E0, int ET,
                         const float* __restrict__ aS, const float* __restrict__ aD,
                         unsigned* __restrict__ mk, int Hh) {
  int e = blockIdx.x * blockDim.x + threadIdx.x;
  if (e >= ET) return;
  int s, d;
  edge_nodes(ei, E0, e, s, d);
  for (int h = 0; h < Hh; ++h) {
    float v = aS[s * Hh + h] + aD[d * Hh + h];
    v = v > 0.f ? v : 0.2f * v;  // leaky_relu
    atomicMax(&mk[d * Hh + h], fkey(v));
  }
}

__global__ void edge_expsum(const int* __restrict__ ei, int E0, int ET,
                            const float* __restrict__ aS, const float* __restrict__ aD,
                            const unsigned* __restrict__ mk, float* __restrict__ ssum,
                            float* __restrict__ exb, int Hh) {
  int e = blockIdx.x * blockDim.x + threadIdx.x;
  if (e >= ET) return;
  int s, d;
  edge_nodes(ei, E0, e, s, d);
  for (int h = 0; h < Hh; ++h) {
    float v = aS[s * Hh + h] + aD[d * Hh + h];
    v = v > 0.f ? v : 0.2f * v;
    float m = unfkey(mk[d * Hh + h]);
    float ex = expf(v - m);
    exb[e * Hh + h] = ex;
    atomicAdd(&ssum[d * Hh + h], ex);
  }
}

// one block per edge; gathers h[src] and atomically accumulates into out[dst]
__global__ void edge_scatter(const int* __restrict__ ei, int E0, int ET,
                             const float* __restrict__ Hf, const float* __restrict__ exb,
                             const float* __restrict__ ssum, float* __restrict__ out,
                             int Hh, int HC) {
  int e = blockIdx.x;
  if (e >= ET) return;
  int s, d;
  edge_nodes(ei, E0, e, s, d);
  for (int c = threadIdx.x; c < HC; c += blockDim.x) {
    int h = c >> 7;  // C = 128 always
    float alpha = exb[e * Hh + h] / ssum[d * Hh + h];
    atomicAdd(&out[(size_t)d * HC + c], Hf[(size_t)s * HC + c] * alpha);
  }
}

// ---------------- bias + activation (mode 0 = ELU, 1 = ReLU) ----------------
__global__ void bias_act(float* __restrict__ x, const float* __restrict__ b, int total,
                         int HC, int mode) {
  int i = blockIdx.x * blockDim.x + threadIdx.x;
  if (i >= total) return;
  float v = x[i] + b[i % HC];
  if (mode == 0)
    v = v > 0.f ? v : expm1f(v);
  else
    v = v > 0.f ? v : 0.f;
  x[i] = v;
}

// ---------------- FC2 + sigmoid: one wave per node, K=64 ----------------
__global__ void fc2_sigmoid(const float* __restrict__ Hin, const float* __restrict__ w,
                            const float* __restrict__ b, float* __restrict__ out, int N) {
  int wid = (int)((blockIdx.x * blockDim.x + threadIdx.x) >> 6);
  int lane = threadIdx.x & 63;
  if (wid >= N) return;
  float v = Hin[(size_t)wid * 64 + lane] * w[lane];
#pragma unroll
  for (int o = 32; o; o >>= 1) v += __shfl_down(v, o);
  if (lane == 0) out[wid] = 1.f / (1.f + expf(-(v + b[0])));
}

// ---------------- launch ----------------
extern "C" void kernel_launch(void* const* d_in, const int* in_sizes, int n_in,
                              void* d_out, int out_size, void* d_ws, size_t ws_size,
                              hipStream_t stream) {
  const float* x    = (const float*)d_in[0];
  const int*   ei   = (const int*)d_in[1];
  const float* W1   = (const float*)d_in[2];
  const float* as1  = (const float*)d_in[3];
  const float* ad1  = (const float*)d_in[4];
  const float* b1   = (const float*)d_in[5];
  const float* W2   = (const float*)d_in[6];
  const float* as2  = (const float*)d_in[7];
  const float* ad2  = (const float*)d_in[8];
  const float* b2   = (const float*)d_in[9];
  const float* W3   = (const float*)d_in[10];
  const float* as3  = (const float*)d_in[11];
  const float* ad3  = (const float*)d_in[12];
  const float* b3   = (const float*)d_in[13];
  const float* fc1w = (const float*)d_in[14];
  const float* fc1b = (const float*)d_in[15];
  const float* fc2w = (const float*)d_in[16];
  const float* fc2b = (const float*)d_in[17];
  float* out = (float*)d_out;

  const int N  = in_sizes[0] / 64;  // 50000
  const int E0 = in_sizes[1] / 2;   // 400000
  const int ET = E0 + N;            // 450000 (incl. self-loops)

  char* ws = (char*)d_ws;
  size_t off = 0;
  auto alloc = [&](size_t bytes) -> void* {
    void* p = ws + off;
    off += (bytes + 255) & ~(size_t)255;
    return p;
  };
  float*    bufH = (float*)alloc((size_t)N * 512 * 4);  // X @ W
  float*    bufO = (float*)alloc((size_t)N * 512 * 4);  // aggregated output / next input
  float*    aS   = (float*)alloc((size_t)N * 4 * 4);
  float*    aD   = (float*)alloc((size_t)N * 4 * 4);
  unsigned* mk   = (unsigned*)alloc((size_t)N * 4 * 4);
  float*    ssum = (float*)alloc((size_t)N * 4 * 4);
  float*    exb  = (float*)alloc((size_t)ET * 4 * 4);
  (void)ws_size; (void)n_in; (void)out_size;

  auto gat_layer = [&](const float* X, int K, const float* W, const float* a_s,
                       const float* a_d, const float* bias, int Hh) {
    const int HC = Hh * 128;
    dim3 gg(HC / 64, (N + 63) / 64);
    hipLaunchKernelGGL(gemm_f32, gg, dim3(256), 0, stream, X, W, bufH, N, HC, K);
    int waves = N * Hh;
    hipLaunchKernelGGL(calc_alpha, dim3((waves + 3) / 4), dim3(256), 0, stream, bufH, a_s,
                       a_d, aS, aD, N, Hh);
    hipMemsetAsync(mk, 0, (size_t)N * Hh * 4, stream);
    hipMemsetAsync(ssum, 0, (size_t)N * Hh * 4, stream);
    hipMemsetAsync(bufO, 0, (size_t)N * HC * 4, stream);
    int eb = (ET + 255) / 256;
    hipLaunchKernelGGL(edge_max, dim3(eb), dim3(256), 0, stream, ei, E0, ET, aS, aD, mk, Hh);
    hipLaunchKernelGGL(edge_expsum, dim3(eb), dim3(256), 0, stream, ei, E0, ET, aS, aD, mk,
                       ssum, exb, Hh);
    hipLaunchKernelGGL(edge_scatter, dim3(ET), dim3(256), 0, stream, ei, E0, ET, bufH, exb,
                       ssum, bufO, Hh, HC);
    hipLaunchKernelGGL(bias_act, dim3(((size_t)N * HC + 255) / 256), dim3(256), 0, stream,
                       bufO, bias, N * HC, HC, 0);
  };

  // layer 1: [N,64] -> [N,512]
  gat_layer(x, 64, W1, as1, ad1, b1, 4);
  // layer 2: [N,512] -> [N,512]  (reads bufO via GEMM before bufO is re-zeroed)
  gat_layer(bufO, 512, W2, as2, ad2, b2, 4);
  // layer 3: [N,512] -> [N,128], heads=1
  gat_layer(bufO, 512, W3, as3, ad3, b3, 1);

  // FC1: [N,128] @ [128,64] + bias, ReLU
  hipLaunchKernelGGL(gemm_f32, dim3(1, (N + 63) / 64), dim3(256), 0, stream, bufO, fc1w,
                     bufH, N, 64, 128);
  hipLaunchKernelGGL(bias_act, dim3((N * 64 + 255) / 256), dim3(256), 0, stream, bufH, fc1b,
                     N * 64, 64, 1);
  // FC2 + sigmoid -> out [N,1]
  hipLaunchKernelGGL(fc2_sigmoid, dim3((N + 3) / 4), dim3(256), 0, stream, bufH, fc2w, fc2b,
                     out, N);
}

// Round 2
// 1364.257 us; speedup vs baseline: 2.0661x; 2.0661x over previous
//
#include <hip/hip_runtime.h>
#include <math.h>

// ---------------- GEMM (f32, 128x128 tile, 8x8/thread, BK=8) ----------------
// A:[M,K] row-major, B:[K,N] row-major, C:[M,N]. Requires N%128==0, K%8==0.
__global__ __launch_bounds__(256) void gemm_f32_128(const float* __restrict__ A,
                                                    const float* __restrict__ B,
                                                    float* __restrict__ C,
                                                    int M, int N, int K) {
  __shared__ float As[8][128];  // As[k][m]
  __shared__ float Bs[8][128];  // Bs[k][n]
  const int tid = threadIdx.x;
  const int tx = tid & 15, ty = tid >> 4;
  const int nBase = blockIdx.x * 128;
  const int mBase = blockIdx.y * 128;
  const int aRow = tid >> 1;          // 0..127
  const int aK   = (tid & 1) * 4;     // 0 or 4
  const int bK   = tid >> 5;          // 0..7
  const int bN   = (tid & 31) * 4;    // 0..124
  float acc[8][8] = {};
  for (int k0 = 0; k0 < K; k0 += 8) {
    float4 av = make_float4(0.f, 0.f, 0.f, 0.f);
    int gr = mBase + aRow;
    if (gr < M) av = *(const float4*)&A[(size_t)gr * K + k0 + aK];
    As[aK + 0][aRow] = av.x;
    As[aK + 1][aRow] = av.y;
    As[aK + 2][aRow] = av.z;
    As[aK + 3][aRow] = av.w;
    float4 bv = *(const float4*)&B[(size_t)(k0 + bK) * N + nBase + bN];
    *(float4*)&Bs[bK][bN] = bv;
    __syncthreads();
#pragma unroll
    for (int k = 0; k < 8; ++k) {
      float4 a0 = *(const float4*)&As[k][ty * 8];
      float4 a1 = *(const float4*)&As[k][ty * 8 + 4];
      float4 b0 = *(const float4*)&Bs[k][tx * 8];
      float4 b1 = *(const float4*)&Bs[k][tx * 8 + 4];
      float ar[8] = {a0.x, a0.y, a0.z, a0.w, a1.x, a1.y, a1.z, a1.w};
      float br[8] = {b0.x, b0.y, b0.z, b0.w, b1.x, b1.y, b1.z, b1.w};
#pragma unroll
      for (int i = 0; i < 8; ++i)
#pragma unroll
        for (int j = 0; j < 8; ++j) acc[i][j] = fmaf(ar[i], br[j], acc[i][j]);
    }
    __syncthreads();
  }
#pragma unroll
  for (int i = 0; i < 8; ++i) {
    int gr = mBase + ty * 8 + i;
    if (gr < M) {
      *(float4*)&C[(size_t)gr * N + nBase + tx * 8] =
          make_float4(acc[i][0], acc[i][1], acc[i][2], acc[i][3]);
      *(float4*)&C[(size_t)gr * N + nBase + tx * 8 + 4] =
          make_float4(acc[i][4], acc[i][5], acc[i][6], acc[i][7]);
    }
  }
}

// ---------------- GEMM (f32, 64x64 tile) for FC1 (N=64) ----------------
__global__ __launch_bounds__(256) void gemm_f32(const float* __restrict__ A,
                                                const float* __restrict__ B,
                                                float* __restrict__ C,
                                                int M, int N, int K) {
  __shared__ float As[16][64];
  __shared__ float Bs[16][64];
  const int tid = threadIdx.x;
  const int tx = tid & 15, ty = tid >> 4;
  const int nBase = blockIdx.x * 64;
  const int mBase = blockIdx.y * 64;
  const int aRow = tid >> 2;
  const int aK   = (tid & 3) << 2;
  const int bC   = tid & 63;
  const int bR0  = tid >> 6;
  float acc[4][4] = {};
  for (int k0 = 0; k0 < K; k0 += 16) {
    float4 av = make_float4(0.f, 0.f, 0.f, 0.f);
    int gr = mBase + aRow;
    if (gr < M) av = *(const float4*)&A[(size_t)gr * K + k0 + aK];
    As[aK + 0][aRow] = av.x;
    As[aK + 1][aRow] = av.y;
    As[aK + 2][aRow] = av.z;
    As[aK + 3][aRow] = av.w;
#pragma unroll
    for (int i = 0; i < 4; ++i) {
      int r = bR0 + i * 4;
      Bs[r][bC] = B[(size_t)(k0 + r) * N + nBase + bC];
    }
    __syncthreads();
#pragma unroll
    for (int k = 0; k < 16; ++k) {
      float4 a = *(const float4*)&As[k][ty * 4];
      float4 b = *(const float4*)&Bs[k][tx * 4];
      float ar[4] = {a.x, a.y, a.z, a.w};
      float br[4] = {b.x, b.y, b.z, b.w};
#pragma unroll
      for (int i = 0; i < 4; ++i)
#pragma unroll
        for (int j = 0; j < 4; ++j) acc[i][j] = fmaf(ar[i], br[j], acc[i][j]);
    }
    __syncthreads();
  }
#pragma unroll
  for (int i = 0; i < 4; ++i) {
    int gr = mBase + ty * 4 + i;
    if (gr < M)
      *(float4*)&C[(size_t)gr * N + nBase + tx * 4] =
          make_float4(acc[i][0], acc[i][1], acc[i][2], acc[i][3]);
  }
}

// ---------------- alpha_s / alpha_d: one wave per (node, head), C=128 ----------------
__global__ void calc_alpha(const float* __restrict__ H, const float* __restrict__ a_src,
                           const float* __restrict__ a_dst, float* __restrict__ as_out,
                           float* __restrict__ ad_out, int N, int Hh) {
  int wid = (int)((blockIdx.x * blockDim.x + threadIdx.x) >> 6);
  int lane = threadIdx.x & 63;
  if (wid >= N * Hh) return;
  int n = wid / Hh, h = wid % Hh;
  const float* hv = H + (size_t)n * (Hh * 128) + h * 128;
  const float* sv = a_src + h * 128;
  const float* dv = a_dst + h * 128;
  float s = hv[lane] * sv[lane] + hv[lane + 64] * sv[lane + 64];
  float d = hv[lane] * dv[lane] + hv[lane + 64] * dv[lane + 64];
#pragma unroll
  for (int o = 32; o; o >>= 1) {
    s += __shfl_down(s, o);
    d += __shfl_down(d, o);
  }
  if (lane == 0) {
    as_out[wid] = s;
    ad_out[wid] = d;
  }
}

// ---------------- CSR build ----------------
__device__ inline void edge_nodes(const int* __restrict__ ei, int E0, int e, int& s, int& d) {
  if (e < E0) { s = ei[e]; d = ei[E0 + e]; }
  else        { s = e - E0; d = e - E0; }   // self-loop
}

__global__ void deg_count(const int* __restrict__ ei, int E0, int ET, int* __restrict__ deg) {
  int e = blockIdx.x * blockDim.x + threadIdx.x;
  if (e >= ET) return;
  int s, d;
  edge_nodes(ei, E0, e, s, d);
  atomicAdd(&deg[d], 1);
}

// inclusive scan of 2048-element chunks; block sums out
__global__ __launch_bounds__(256) void scan_chunk(const int* __restrict__ deg,
                                                  int* __restrict__ incl,
                                                  int* __restrict__ bsums, int N) {
  __shared__ int sdata[256];
  const int t = threadIdx.x;
  const int base = blockIdx.x * 2048;
  int v[8];
  int sum = 0;
#pragma unroll
  for (int i = 0; i < 8; ++i) {
    int idx = base + t * 8 + i;
    v[i] = (idx < N) ? deg[idx] : 0;
    sum += v[i];
  }
  sdata[t] = sum;
  __syncthreads();
  for (int off = 1; off < 256; off <<= 1) {
    int x = (t >= off) ? sdata[t - off] : 0;
    __syncthreads();
    sdata[t] += x;
    __syncthreads();
  }
  int run = (t > 0) ? sdata[t - 1] : 0;
#pragma unroll
  for (int i = 0; i < 8; ++i) {
    int idx = base + t * 8 + i;
    run += v[i];
    if (idx < N) incl[idx] = run;
  }
  if (t == 255) bsums[blockIdx.x] = sdata[255];
}

// single block: exclusive scan of block sums (nb <= 256)
__global__ __launch_bounds__(256) void scan_bsums(int* __restrict__ bsums, int nb) {
  __shared__ int s[256];
  int t = threadIdx.x;
  s[t] = (t < nb) ? bsums[t] : 0;
  __syncthreads();
  for (int off = 1; off < 256; off <<= 1) {
    int x = (t >= off) ? s[t - off] : 0;
    __syncthreads();
    s[t] += x;
    __syncthreads();
  }
  if (t < nb) bsums[t] = (t == 0) ? 0 : s[t - 1];
}

__global__ void scan_final(const int* __restrict__ incl, const int* __restrict__ bsums,
                           int* __restrict__ rowptr, int N) {
  int i = blockIdx.x * blockDim.x + threadIdx.x;
  if (i < N) rowptr[i + 1] = incl[i] + bsums[i >> 11];
  if (i == 0) rowptr[0] = 0;
}

__global__ void csr_fill(const int* __restrict__ ei, int E0, int ET,
                         const int* __restrict__ rowptr, int* __restrict__ cnt,
                         int* __restrict__ csr_src) {
  int e = blockIdx.x * blockDim.x + threadIdx.x;
  if (e >= ET) return;
  int s, d;
  edge_nodes(ei, E0, e, s, d);
  int pos = atomicAdd(&cnt[d], 1);
  csr_src[rowptr[d] + pos] = s;
}

// ---------------- fused segment-softmax + gather-aggregate + bias + ELU ----------------
// one block (256 threads) per dst node. Hh in {1,4}, HC = Hh*128.
__global__ __launch_bounds__(256) void gat_aggregate(const int* __restrict__ rowptr,
                                                     const int* __restrict__ csr_src,
                                                     const float* __restrict__ H,
                                                     const float* __restrict__ aS,
                                                     const float* __restrict__ aD,
                                                     const float* __restrict__ bias,
                                                     float* __restrict__ out,
                                                     int Hh, int hshift, int HC) {
  __shared__ float sAlpha[512];
  __shared__ int sSrc[128];
  __shared__ float sM[4], sSinv[4];
  const int d = blockIdx.x;
  const int tid = threadIdx.x;
  const int beg = rowptr[d];
  const int deg = rowptr[d + 1] - beg;

  // phase 1: per-head max + expsum over ALL incoming edges (wave 0)
  if (tid < 64) {
    int lane = tid;
    for (int h = 0; h < Hh; ++h) {
      float ad = aD[d * Hh + h];
      float m = -1e30f;
      for (int e = lane; e < deg; e += 64) {
        float l = aS[csr_src[beg + e] * Hh + h] + ad;
        l = l > 0.f ? l : 0.2f * l;
        m = fmaxf(m, l);
      }
#pragma unroll
      for (int o = 32; o; o >>= 1) m = fmaxf(m, __shfl_xor(m, o));
      float ssum = 0.f;
      for (int e = lane; e < deg; e += 64) {
        float l = aS[csr_src[beg + e] * Hh + h] + ad;
        l = l > 0.f ? l : 0.2f * l;
        ssum += expf(l - m);
      }
#pragma unroll
      for (int o = 32; o; o >>= 1) ssum += __shfl_xor(ssum, o);
      if (lane == 0) {
        sM[h] = m;
        sSinv[h] = 1.f / ssum;
      }
    }
  }
  __syncthreads();

  // phase 2: chunked alpha staging + channel accumulation
  const int c2 = tid * 2;
  const bool active = c2 < HC;
  const int h = c2 >> 7;
  float accx = 0.f, accy = 0.f;
  for (int chunk = 0; chunk < deg; chunk += 128) {
    int ce = min(128, deg - chunk);
    if (tid < ce) sSrc[tid] = csr_src[beg + chunk + tid];
    __syncthreads();
    for (int idx = tid; idx < ce * Hh; idx += 256) {
      int e = idx >> hshift;
      int hh = idx - (e << hshift);
      float l = aS[sSrc[e] * Hh + hh] + aD[d * Hh + hh];
      l = l > 0.f ? l : 0.2f * l;
      sAlpha[idx] = expf(l - sM[hh]) * sSinv[hh];
    }
    __syncthreads();
    if (active) {
      for (int e = 0; e < ce; ++e) {
        float a = sAlpha[(e << hshift) + h];
        const float2 hv = *(const float2*)&H[(size_t)sSrc[e] * HC + c2];
        accx = fmaf(a, hv.x, accx);
        accy = fmaf(a, hv.y, accy);
      }
    }
    __syncthreads();
  }
  if (active) {
    float ox = accx + bias[c2];
    float oy = accy + bias[c2 + 1];
    ox = ox > 0.f ? ox : expm1f(ox);
    oy = oy > 0.f ? oy : expm1f(oy);
    *(float2*)&out[(size_t)d * HC + c2] = make_float2(ox, oy);
  }
}

// ---------------- bias + ReLU (FC1 epilogue) ----------------
__global__ void bias_relu(float* __restrict__ x, const float* __restrict__ b, int total,
                          int HC) {
  int i = blockIdx.x * blockDim.x + threadIdx.x;
  if (i >= total) return;
  float v = x[i] + b[i % HC];
  x[i] = v > 0.f ? v : 0.f;
}

// ---------------- FC2 + sigmoid: one wave per node, K=64 ----------------
__global__ void fc2_sigmoid(const float* __restrict__ Hin, const float* __restrict__ w,
                            const float* __restrict__ b, float* __restrict__ out, int N) {
  int wid = (int)((blockIdx.x * blockDim.x + threadIdx.x) >> 6);
  int lane = threadIdx.x & 63;
  if (wid >= N) return;
  float v = Hin[(size_t)wid * 64 + lane] * w[lane];
#pragma unroll
  for (int o = 32; o; o >>= 1) v += __shfl_down(v, o);
  if (lane == 0) out[wid] = 1.f / (1.f + expf(-(v + b[0])));
}

// ---------------- launch ----------------
extern "C" void kernel_launch(void* const* d_in, const int* in_sizes, int n_in,
                              void* d_out, int out_size, void* d_ws, size_t ws_size,
                              hipStream_t stream) {
  const float* x    = (const float*)d_in[0];
  const int*   ei   = (const int*)d_in[1];
  const float* W1   = (const float*)d_in[2];
  const float* as1  = (const float*)d_in[3];
  const float* ad1  = (const float*)d_in[4];
  const float* b1   = (const float*)d_in[5];
  const float* W2   = (const float*)d_in[6];
  const float* as2  = (const float*)d_in[7];
  const float* ad2  = (const float*)d_in[8];
  const float* b2   = (const float*)d_in[9];
  const float* W3   = (const float*)d_in[10];
  const float* as3  = (const float*)d_in[11];
  const float* ad3  = (const float*)d_in[12];
  const float* b3   = (const float*)d_in[13];
  const float* fc1w = (const float*)d_in[14];
  const float* fc1b = (const float*)d_in[15];
  const float* fc2w = (const float*)d_in[16];
  const float* fc2b = (const float*)d_in[17];
  float* out = (float*)d_out;

  const int N  = in_sizes[0] / 64;  // 50000
  const int E0 = in_sizes[1] / 2;   // 400000
  const int ET = E0 + N;            // +self-loops

  char* ws = (char*)d_ws;
  size_t off = 0;
  auto alloc = [&](size_t bytes) -> void* {
    void* p = ws + off;
    off += (bytes + 255) & ~(size_t)255;
    return p;
  };
  float* bufH    = (float*)alloc((size_t)N * 512 * 4);
  float* bufO    = (float*)alloc((size_t)N * 512 * 4);
  float* aS      = (float*)alloc((size_t)N * 4 * 4);
  float* aD      = (float*)alloc((size_t)N * 4 * 4);
  int*   deg     = (int*)alloc((size_t)N * 4);
  int*   cnt     = (int*)alloc((size_t)N * 4);
  int*   incl    = (int*)alloc((size_t)N * 4);
  int*   rowptr  = (int*)alloc((size_t)(N + 1) * 4);
  int*   bsums   = (int*)alloc(256 * 4);
  int*   csr_src = (int*)alloc((size_t)ET * 4);
  (void)ws_size; (void)n_in; (void)out_size;

  // ---- CSR build (once per call; edge list is the same for all layers) ----
  hipMemsetAsync(deg, 0, (size_t)N * 4, stream);
  hipMemsetAsync(cnt, 0, (size_t)N * 4, stream);
  int eb = (ET + 255) / 256;
  hipLaunchKernelGGL(deg_count, dim3(eb), dim3(256), 0, stream, ei, E0, ET, deg);
  int nb = (N + 2047) / 2048;
  hipLaunchKernelGGL(scan_chunk, dim3(nb), dim3(256), 0, stream, deg, incl, bsums, N);
  hipLaunchKernelGGL(scan_bsums, dim3(1), dim3(256), 0, stream, bsums, nb);
  hipLaunchKernelGGL(scan_final, dim3((N + 255) / 256), dim3(256), 0, stream, incl, bsums,
                     rowptr, N);
  hipLaunchKernelGGL(csr_fill, dim3(eb), dim3(256), 0, stream, ei, E0, ET, rowptr, cnt,
                     csr_src);

  auto gat_layer = [&](const float* X, int K, const float* W, const float* a_s,
                       const float* a_d, const float* bias, int Hh) {
    const int HC = Hh * 128;
    const int hshift = (Hh == 4) ? 2 : 0;
    hipLaunchKernelGGL(gemm_f32_128, dim3(HC / 128, (N + 127) / 128), dim3(256), 0, stream,
                       X, W, bufH, N, HC, K);
    int waves = N * Hh;
    hipLaunchKernelGGL(calc_alpha, dim3((waves + 3) / 4), dim3(256), 0, stream, bufH, a_s,
                       a_d, aS, aD, N, Hh);
    hipLaunchKernelGGL(gat_aggregate, dim3(N), dim3(256), 0, stream, rowptr, csr_src, bufH,
                       aS, aD, bias, bufO, Hh, hshift, HC);
  };

  // layer 1: [N,64] -> [N,512]
  gat_layer(x, 64, W1, as1, ad1, b1, 4);
  // layer 2: [N,512] -> [N,512]
  gat_layer(bufO, 512, W2, as2, ad2, b2, 4);
  // layer 3: [N,512] -> [N,128], heads=1
  gat_layer(bufO, 512, W3, as3, ad3, b3, 1);

  // FC1: [N,128] @ [128,64] + bias, ReLU
  hipLaunchKernelGGL(gemm_f32, dim3(1, (N + 63) / 64), dim3(256), 0, stream, bufO, fc1w,
                     bufH, N, 64, 128);
  hipLaunchKernelGGL(bias_relu, dim3((N * 64 + 255) / 256), dim3(256), 0, stream, bufH,
                     fc1b, N * 64, 64);
  // FC2 + sigmoid -> out [N,1]
  hipLaunchKernelGGL(fc2_sigmoid, dim3((N + 3) / 4), dim3(256), 0, stream, bufH, fc2w, fc2b,
                     out, N);
}

// Round 3
// 882.004 us; speedup vs baseline: 3.1958x; 1.5468x over previous
//
#include <hip/hip_runtime.h>
#include <math.h>

typedef __attribute__((ext_vector_type(8))) short short8;
typedef __attribute__((ext_vector_type(4))) float f32x4;
typedef unsigned short u16;
typedef unsigned int u32;

__device__ inline u16 f2b(float f) {  // f32 -> bf16 round-to-nearest-even
  u32 u = __float_as_uint(f);
  return (u16)((u + 0x7FFFu + ((u >> 16) & 1u)) >> 16);
}
__device__ inline float b2f(u16 b) { return __uint_as_float((u32)b << 16); }

__device__ inline void gld_lds16(const void* g, void* l) {
  __builtin_amdgcn_global_load_lds((const __attribute__((address_space(1))) void*)g,
                                   (__attribute__((address_space(3))) void*)l, 16, 0, 0);
}

// ---------------- casts ----------------
__global__ void cast_f32_bf16(const float* __restrict__ src, u16* __restrict__ dst, int n) {
  int i = blockIdx.x * blockDim.x + threadIdx.x;
  if (i < n) dst[i] = f2b(src[i]);
}

// W [K,HC] f32 -> Wt [HC,K] bf16
__global__ void cast_transpose_w(const float* __restrict__ W, u16* __restrict__ Wt, int K,
                                 int HC) {
  int i = blockIdx.x * blockDim.x + threadIdx.x;
  if (i >= K * HC) return;
  int k = i / HC, n = i % HC;
  Wt[(size_t)n * K + k] = f2b(W[i]);
}

// ---------------- bf16 MFMA GEMM with fused alpha epilogue ----------------
// A:[M,K] bf16 row-major, Bt:[HC,K] bf16 row-major (=W^T). C = A@W written as bf16 Hb.
// Each block: 128x128 tile; block-col covers exactly one head (128 ch).
// Epilogue also computes aS[row,h] = sum_c H*a_src[h,c], aD likewise (f32, exact from acc).
__global__ __launch_bounds__(256) void gemm_bf16_gat(
    const u16* __restrict__ A, const u16* __restrict__ Bt, u16* __restrict__ Hb,
    const float* __restrict__ a_src, const float* __restrict__ a_dst,
    float* __restrict__ aS, float* __restrict__ aD, int M, int HC, int K, int Hh) {
  __shared__ u16 As[128 * 32];
  __shared__ u16 Bs[128 * 32];
  __shared__ float sRed[2][2][128];
  const int tid = threadIdx.x;
  const int w = tid >> 6, lane = tid & 63;
  const int wm = w >> 1, wn = w & 1;
  const int q = lane >> 4, l15 = lane & 15;
  const int nBase = blockIdx.x * 128;
  const int mBase = blockIdx.y * 128;
  const int h = nBase >> 7;
  const int srow = lane >> 2;        // 0..15
  const int skc = (lane & 3) * 8;    // bf16 elems 0,8,16,24

  f32x4 acc[4][4];
#pragma unroll
  for (int i = 0; i < 4; ++i)
#pragma unroll
    for (int j = 0; j < 4; ++j) acc[i][j] = (f32x4){0.f, 0.f, 0.f, 0.f};

  for (int k0 = 0; k0 < K; k0 += 32) {
#pragma unroll
    for (int r = 0; r < 2; ++r) {
      int lrow = w * 32 + r * 16 + srow;
      int ga = mBase + lrow;
      if (ga >= M) ga = M - 1;
      gld_lds16(A + (size_t)ga * K + k0 + skc, &As[(w * 32 + r * 16) * 32]);
      int gb = nBase + lrow;  // < HC always
      gld_lds16(Bt + (size_t)gb * K + k0 + skc, &Bs[(w * 32 + r * 16) * 32]);
    }
    __syncthreads();
    short8 af[4], bf[4];
#pragma unroll
    for (int i = 0; i < 4; ++i)
      af[i] = *(const short8*)&As[(wm * 64 + i * 16 + l15) * 32 + q * 8];
#pragma unroll
    for (int j = 0; j < 4; ++j)
      bf[j] = *(const short8*)&Bs[(wn * 64 + j * 16 + l15) * 32 + q * 8];
#pragma unroll
    for (int i = 0; i < 4; ++i)
#pragma unroll
      for (int j = 0; j < 4; ++j)
        acc[i][j] = __builtin_amdgcn_mfma_f32_16x16x32_bf16(af[i], bf[j], acc[i][j], 0, 0, 0);
    __syncthreads();
  }

  // epilogue: store bf16 H + fused alpha dot products
  float asv[4], adv[4];
#pragma unroll
  for (int j = 0; j < 4; ++j) {
    int cw = wn * 64 + j * 16 + l15;  // col within head 0..127
    asv[j] = a_src[h * 128 + cw];
    adv[j] = a_dst[h * 128 + cw];
  }
#pragma unroll
  for (int mi = 0; mi < 4; ++mi) {
#pragma unroll
    for (int r = 0; r < 4; ++r) {
      int row = mBase + wm * 64 + mi * 16 + q * 4 + r;
      float s = 0.f, d = 0.f;
#pragma unroll
      for (int j = 0; j < 4; ++j) {
        float v = acc[mi][j][r];
        s = fmaf(v, asv[j], s);
        d = fmaf(v, adv[j], d);
        if (row < M) Hb[(size_t)row * HC + nBase + wn * 64 + j * 16 + l15] = f2b(v);
      }
#pragma unroll
      for (int o = 8; o; o >>= 1) {
        s += __shfl_xor(s, o);
        d += __shfl_xor(d, o);
      }
      if (l15 == 0) {
        int lr = wm * 64 + mi * 16 + q * 4 + r;
        sRed[0][wn][lr] = s;
        sRed[1][wn][lr] = d;
      }
    }
  }
  __syncthreads();
  if (tid < 128) {
    int row = mBase + tid;
    if (row < M) {
      aS[(size_t)row * Hh + h] = sRed[0][0][tid] + sRed[0][1][tid];
      aD[(size_t)row * Hh + h] = sRed[1][0][tid] + sRed[1][1][tid];
    }
  }
}

// ---------------- CSR build ----------------
__device__ inline void edge_nodes(const int* __restrict__ ei, int E0, int e, int& s, int& d) {
  if (e < E0) { s = ei[e]; d = ei[E0 + e]; }
  else        { s = e - E0; d = e - E0; }
}

__global__ void deg_count(const int* __restrict__ ei, int E0, int ET, int* __restrict__ deg) {
  int e = blockIdx.x * blockDim.x + threadIdx.x;
  if (e >= ET) return;
  int s, d;
  edge_nodes(ei, E0, e, s, d);
  atomicAdd(&deg[d], 1);
}

__global__ __launch_bounds__(256) void scan_chunk(const int* __restrict__ deg,
                                                  int* __restrict__ incl,
                                                  int* __restrict__ bsums, int N) {
  __shared__ int sdata[256];
  const int t = threadIdx.x;
  const int base = blockIdx.x * 2048;
  int v[8];
  int sum = 0;
#pragma unroll
  for (int i = 0; i < 8; ++i) {
    int idx = base + t * 8 + i;
    v[i] = (idx < N) ? deg[idx] : 0;
    sum += v[i];
  }
  sdata[t] = sum;
  __syncthreads();
  for (int off = 1; off < 256; off <<= 1) {
    int x = (t >= off) ? sdata[t - off] : 0;
    __syncthreads();
    sdata[t] += x;
    __syncthreads();
  }
  int run = (t > 0) ? sdata[t - 1] : 0;
#pragma unroll
  for (int i = 0; i < 8; ++i) {
    int idx = base + t * 8 + i;
    run += v[i];
    if (idx < N) incl[idx] = run;
  }
  if (t == 255) bsums[blockIdx.x] = sdata[255];
}

__global__ __launch_bounds__(256) void scan_bsums(int* __restrict__ bsums, int nb) {
  __shared__ int s[256];
  int t = threadIdx.x;
  s[t] = (t < nb) ? bsums[t] : 0;
  __syncthreads();
  for (int off = 1; off < 256; off <<= 1) {
    int x = (t >= off) ? s[t - off] : 0;
    __syncthreads();
    s[t] += x;
    __syncthreads();
  }
  if (t < nb) bsums[t] = (t == 0) ? 0 : s[t - 1];
}

__global__ void scan_final(const int* __restrict__ incl, const int* __restrict__ bsums,
                           int* __restrict__ rowptr, int N) {
  int i = blockIdx.x * blockDim.x + threadIdx.x;
  if (i < N) rowptr[i + 1] = incl[i] + bsums[i >> 11];
  if (i == 0) rowptr[0] = 0;
}

__global__ void csr_fill(const int* __restrict__ ei, int E0, int ET,
                         const int* __restrict__ rowptr, int* __restrict__ cnt,
                         int* __restrict__ csr_src) {
  int e = blockIdx.x * blockDim.x + threadIdx.x;
  if (e >= ET) return;
  int s, d;
  edge_nodes(ei, E0, e, s, d);
  int pos = atomicAdd(&cnt[d], 1);
  csr_src[rowptr[d] + pos] = s;
}

// ---------------- fused softmax + bf16 gather-aggregate + bias + ELU ----------------
// one block per dst node; lane-group handles 8 channels (16B bf16); multiple edges in flight.
__global__ __launch_bounds__(256) void gat_aggregate2(
    const int* __restrict__ rowptr, const int* __restrict__ csr_src,
    const u16* __restrict__ Hb, const float* __restrict__ aS, const float* __restrict__ aD,
    const float* __restrict__ bias, u16* __restrict__ outB, float* __restrict__ outF,
    int Hh, int hshift, int HC) {
  __shared__ int sSrc[64];
  __shared__ float sAlpha[256];
  __shared__ float sM[4], sSinv[4];
  __shared__ float sRed[256][9];  // +1 pad breaks 8-float stride conflicts
  const int d = blockIdx.x;
  const int tid = threadIdx.x;
  const int beg = rowptr[d];
  const int deg = rowptr[d + 1] - beg;
  const int cg = HC >> 3;          // channel groups (64 or 16)
  const int cslot = tid & (cg - 1);
  const int eslot = tid / cg;
  const int egN = 256 / cg;        // edges in flight (4 or 16)
  const int c0 = cslot * 8;
  const int h = c0 >> 7;

  // phase 1: per-head max + expsum (wave 0)
  if (tid < 64) {
    for (int hh = 0; hh < Hh; ++hh) {
      float adv = aD[d * Hh + hh];
      float m = -1e30f;
      for (int e = tid; e < deg; e += 64) {
        float l = aS[csr_src[beg + e] * Hh + hh] + adv;
        l = l > 0.f ? l : 0.2f * l;
        m = fmaxf(m, l);
      }
#pragma unroll
      for (int o = 32; o; o >>= 1) m = fmaxf(m, __shfl_xor(m, o));
      float ss = 0.f;
      for (int e = tid; e < deg; e += 64) {
        float l = aS[csr_src[beg + e] * Hh + hh] + adv;
        l = l > 0.f ? l : 0.2f * l;
        ss += expf(l - m);
      }
#pragma unroll
      for (int o = 32; o; o >>= 1) ss += __shfl_xor(ss, o);
      if (tid == 0) {
        sM[hh] = m;
        sSinv[hh] = 1.f / ss;
      }
    }
  }
  __syncthreads();

  float acc[8] = {};
  for (int chunk = 0; chunk < deg; chunk += 64) {
    int ce = min(64, deg - chunk);
    if (tid < ce) sSrc[tid] = csr_src[beg + chunk + tid];
    __syncthreads();
    for (int idx = tid; idx < (ce << hshift); idx += 256) {
      int e = idx >> hshift;
      int hh = idx & (Hh - 1);
      float l = aS[sSrc[e] * Hh + hh] + aD[d * Hh + hh];
      l = l > 0.f ? l : 0.2f * l;
      sAlpha[idx] = expf(l - sM[hh]) * sSinv[hh];
    }
    __syncthreads();
    for (int e = eslot; e < ce; e += egN) {
      float a = sAlpha[(e << hshift) + h];
      uint4 pv = *(const uint4*)&Hb[(size_t)sSrc[e] * HC + c0];
      acc[0] = fmaf(a, b2f((u16)(pv.x & 0xffff)), acc[0]);
      acc[1] = fmaf(a, b2f((u16)(pv.x >> 16)), acc[1]);
      acc[2] = fmaf(a, b2f((u16)(pv.y & 0xffff)), acc[2]);
      acc[3] = fmaf(a, b2f((u16)(pv.y >> 16)), acc[3]);
      acc[4] = fmaf(a, b2f((u16)(pv.z & 0xffff)), acc[4]);
      acc[5] = fmaf(a, b2f((u16)(pv.z >> 16)), acc[5]);
      acc[6] = fmaf(a, b2f((u16)(pv.w & 0xffff)), acc[6]);
      acc[7] = fmaf(a, b2f((u16)(pv.w >> 16)), acc[7]);
    }
    __syncthreads();
  }
#pragma unroll
  for (int i = 0; i < 8; ++i) sRed[tid][i] = acc[i];
  __syncthreads();
  if (tid < cg) {
    float tot[8];
#pragma unroll
    for (int i = 0; i < 8; ++i) tot[i] = sRed[tid][i];
    for (int e = 1; e < egN; ++e)
#pragma unroll
      for (int i = 0; i < 8; ++i) tot[i] += sRed[e * cg + tid][i];
    u16 packed[8];
#pragma unroll
    for (int i = 0; i < 8; ++i) {
      float v = tot[i] + bias[c0 + i];
      v = v > 0.f ? v : expm1f(v);
      tot[i] = v;
      packed[i] = f2b(v);
    }
    if (outB) *(uint4*)&outB[(size_t)d * HC + c0] = *(const uint4*)packed;
    if (outF) {
      *(float4*)&outF[(size_t)d * HC + c0] = make_float4(tot[0], tot[1], tot[2], tot[3]);
      *(float4*)&outF[(size_t)d * HC + c0 + 4] = make_float4(tot[4], tot[5], tot[6], tot[7]);
    }
  }
}

// ---------------- FC head (f32, tiny) ----------------
__global__ __launch_bounds__(256) void gemm_f32(const float* __restrict__ A,
                                                const float* __restrict__ B,
                                                float* __restrict__ C,
                                                int M, int N, int K) {
  __shared__ float As[16][64];
  __shared__ float Bs[16][64];
  const int tid = threadIdx.x;
  const int tx = tid & 15, ty = tid >> 4;
  const int nBase = blockIdx.x * 64;
  const int mBase = blockIdx.y * 64;
  const int aRow = tid >> 2;
  const int aK = (tid & 3) << 2;
  const int bC = tid & 63;
  const int bR0 = tid >> 6;
  float acc[4][4] = {};
  for (int k0 = 0; k0 < K; k0 += 16) {
    float4 av = make_float4(0.f, 0.f, 0.f, 0.f);
    int gr = mBase + aRow;
    if (gr < M) av = *(const float4*)&A[(size_t)gr * K + k0 + aK];
    As[aK + 0][aRow] = av.x;
    As[aK + 1][aRow] = av.y;
    As[aK + 2][aRow] = av.z;
    As[aK + 3][aRow] = av.w;
#pragma unroll
    for (int i = 0; i < 4; ++i) {
      int r = bR0 + i * 4;
      Bs[r][bC] = B[(size_t)(k0 + r) * N + nBase + bC];
    }
    __syncthreads();
#pragma unroll
    for (int k = 0; k < 16; ++k) {
      float4 a = *(const float4*)&As[k][ty * 4];
      float4 b = *(const float4*)&Bs[k][tx * 4];
      float ar[4] = {a.x, a.y, a.z, a.w};
      float br[4] = {b.x, b.y, b.z, b.w};
#pragma unroll
      for (int i = 0; i < 4; ++i)
#pragma unroll
        for (int j = 0; j < 4; ++j) acc[i][j] = fmaf(ar[i], br[j], acc[i][j]);
    }
    __syncthreads();
  }
#pragma unroll
  for (int i = 0; i < 4; ++i) {
    int gr = mBase + ty * 4 + i;
    if (gr < M)
      *(float4*)&C[(size_t)gr * N + nBase + tx * 4] =
          make_float4(acc[i][0], acc[i][1], acc[i][2], acc[i][3]);
  }
}

__global__ void bias_relu(float* __restrict__ x, const float* __restrict__ b, int total,
                          int HC) {
  int i = blockIdx.x * blockDim.x + threadIdx.x;
  if (i >= total) return;
  float v = x[i] + b[i % HC];
  x[i] = v > 0.f ? v : 0.f;
}

__global__ void fc2_sigmoid(const float* __restrict__ Hin, const float* __restrict__ w,
                            const float* __restrict__ b, float* __restrict__ out, int N) {
  int wid = (int)((blockIdx.x * blockDim.x + threadIdx.x) >> 6);
  int lane = threadIdx.x & 63;
  if (wid >= N) return;
  float v = Hin[(size_t)wid * 64 + lane] * w[lane];
#pragma unroll
  for (int o = 32; o; o >>= 1) v += __shfl_down(v, o);
  if (lane == 0) out[wid] = 1.f / (1.f + expf(-(v + b[0])));
}

// ---------------- launch ----------------
extern "C" void kernel_launch(void* const* d_in, const int* in_sizes, int n_in,
                              void* d_out, int out_size, void* d_ws, size_t ws_size,
                              hipStream_t stream) {
  const float* x    = (const float*)d_in[0];
  const int*   ei   = (const int*)d_in[1];
  const float* W1   = (const float*)d_in[2];
  const float* as1  = (const float*)d_in[3];
  const float* ad1  = (const float*)d_in[4];
  const float* b1   = (const float*)d_in[5];
  const float* W2   = (const float*)d_in[6];
  const float* as2  = (const float*)d_in[7];
  const float* ad2  = (const float*)d_in[8];
  const float* b2   = (const float*)d_in[9];
  const float* W3   = (const float*)d_in[10];
  const float* as3  = (const float*)d_in[11];
  const float* ad3  = (const float*)d_in[12];
  const float* b3   = (const float*)d_in[13];
  const float* fc1w = (const float*)d_in[14];
  const float* fc1b = (const float*)d_in[15];
  const float* fc2w = (const float*)d_in[16];
  const float* fc2b = (const float*)d_in[17];
  float* out = (float*)d_out;

  const int N  = in_sizes[0] / 64;  // 50000
  const int E0 = in_sizes[1] / 2;   // 400000
  const int ET = E0 + N;

  char* ws = (char*)d_ws;
  size_t off = 0;
  auto alloc = [&](size_t bytes) -> void* {
    void* p = ws + off;
    off += (bytes + 255) & ~(size_t)255;
    return p;
  };
  u16*   bufXb   = (u16*)alloc((size_t)N * 512 * 2);   // GEMM input (bf16)
  u16*   bufHb   = (u16*)alloc((size_t)N * 512 * 2);   // GEMM output H (bf16)
  float* bufF    = (float*)alloc((size_t)N * 128 * 4); // layer3 agg out (f32)
  float* bufF2   = (float*)alloc((size_t)N * 64 * 4);  // FC1 out
  float* aS      = (float*)alloc((size_t)N * 4 * 4);
  float* aD      = (float*)alloc((size_t)N * 4 * 4);
  u16*   Wt1     = (u16*)alloc((size_t)512 * 64 * 2);
  u16*   Wt2     = (u16*)alloc((size_t)512 * 512 * 2);
  u16*   Wt3     = (u16*)alloc((size_t)128 * 512 * 2);
  int*   deg     = (int*)alloc((size_t)N * 4);
  int*   cnt     = (int*)alloc((size_t)N * 4);
  int*   incl    = (int*)alloc((size_t)N * 4);
  int*   rowptr  = (int*)alloc((size_t)(N + 1) * 4);
  int*   bsums   = (int*)alloc(256 * 4);
  int*   csr_src = (int*)alloc((size_t)ET * 4);
  (void)ws_size; (void)n_in; (void)out_size;

  // ---- upfront casts ----
  hipLaunchKernelGGL(cast_f32_bf16, dim3((N * 64 + 255) / 256), dim3(256), 0, stream, x,
                     bufXb, N * 64);
  hipLaunchKernelGGL(cast_transpose_w, dim3((64 * 512 + 255) / 256), dim3(256), 0, stream,
                     W1, Wt1, 64, 512);
  hipLaunchKernelGGL(cast_transpose_w, dim3((512 * 512 + 255) / 256), dim3(256), 0, stream,
                     W2, Wt2, 512, 512);
  hipLaunchKernelGGL(cast_transpose_w, dim3((512 * 128 + 255) / 256), dim3(256), 0, stream,
                     W3, Wt3, 512, 128);

  // ---- CSR build ----
  hipMemsetAsync(deg, 0, (size_t)N * 4, stream);
  hipMemsetAsync(cnt, 0, (size_t)N * 4, stream);
  int eb = (ET + 255) / 256;
  hipLaunchKernelGGL(deg_count, dim3(eb), dim3(256), 0, stream, ei, E0, ET, deg);
  int nb = (N + 2047) / 2048;
  hipLaunchKernelGGL(scan_chunk, dim3(nb), dim3(256), 0, stream, deg, incl, bsums, N);
  hipLaunchKernelGGL(scan_bsums, dim3(1), dim3(256), 0, stream, bsums, nb);
  hipLaunchKernelGGL(scan_final, dim3((N + 255) / 256), dim3(256), 0, stream, incl, bsums,
                     rowptr, N);
  hipLaunchKernelGGL(csr_fill, dim3(eb), dim3(256), 0, stream, ei, E0, ET, rowptr, cnt,
                     csr_src);

  const int gy = (N + 127) / 128;
  auto gat_layer = [&](int K, const u16* Wt, const float* a_s, const float* a_d,
                       const float* bias, int Hh, u16* aggB, float* aggF) {
    const int HC = Hh * 128;
    const int hshift = (Hh == 4) ? 2 : 0;
    hipLaunchKernelGGL(gemm_bf16_gat, dim3(HC / 128, gy), dim3(256), 0, stream, bufXb, Wt,
                       bufHb, a_s, a_d, aS, aD, N, HC, K, Hh);
    hipLaunchKernelGGL(gat_aggregate2, dim3(N), dim3(256), 0, stream, rowptr, csr_src,
                       bufHb, aS, aD, bias, aggB, aggF, Hh, hshift, HC);
  };

  gat_layer(64,  Wt1, as1, ad1, b1, 4, bufXb, nullptr);   // layer 1 -> bufXb (bf16)
  gat_layer(512, Wt2, as2, ad2, b2, 4, bufXb, nullptr);   // layer 2 -> bufXb (bf16)
  gat_layer(512, Wt3, as3, ad3, b3, 1, nullptr, bufF);    // layer 3 -> bufF (f32)

  hipLaunchKernelGGL(gemm_f32, dim3(1, (N + 63) / 64), dim3(256), 0, stream, bufF, fc1w,
                     bufF2, N, 64, 128);
  hipLaunchKernelGGL(bias_relu, dim3((N * 64 + 255) / 256), dim3(256), 0, stream, bufF2,
                     fc1b, N * 64, 64);
  hipLaunchKernelGGL(fc2_sigmoid, dim3((N + 3) / 4), dim3(256), 0, stream, bufF2, fc2w,
                     fc2b, out, N);
}

// Round 4
// 683.659 us; speedup vs baseline: 4.1230x; 1.2901x over previous
//
#include <hip/hip_runtime.h>
#include <math.h>

typedef __attribute__((ext_vector_type(8))) short short8;
typedef __attribute__((ext_vector_type(4))) float f32x4;
typedef unsigned short u16;
typedef unsigned int u32;

__device__ inline u16 f2b(float f) {  // f32 -> bf16 round-to-nearest-even
  u32 u = __float_as_uint(f);
  return (u16)((u + 0x7FFFu + ((u >> 16) & 1u)) >> 16);
}
__device__ inline float b2f(u16 b) { return __uint_as_float((u32)b << 16); }
__device__ inline float lrelu(float v) { return v > 0.f ? v : 0.2f * v; }

__device__ inline void gld_lds16(const void* g, void* l) {
  __builtin_amdgcn_global_load_lds((const __attribute__((address_space(1))) void*)g,
                                   (__attribute__((address_space(3))) void*)l, 16, 0, 0);
}

// ---------------- casts ----------------
__global__ void cast_f32_bf16(const float* __restrict__ src, u16* __restrict__ dst, int n) {
  int i = blockIdx.x * blockDim.x + threadIdx.x;
  if (i < n) dst[i] = f2b(src[i]);
}

// W [K,HC] f32 -> Wt [HC,K] bf16
__global__ void cast_transpose_w(const float* __restrict__ W, u16* __restrict__ Wt, int K,
                                 int HC) {
  int i = blockIdx.x * blockDim.x + threadIdx.x;
  if (i >= K * HC) return;
  int k = i / HC, n = i % HC;
  Wt[(size_t)n * K + k] = f2b(W[i]);
}

// ---------------- bf16 MFMA GEMM with fused alpha epilogue ----------------
__global__ __launch_bounds__(256) void gemm_bf16_gat(
    const u16* __restrict__ A, const u16* __restrict__ Bt, u16* __restrict__ Hb,
    const float* __restrict__ a_src, const float* __restrict__ a_dst,
    float* __restrict__ aS, float* __restrict__ aD, int M, int HC, int K, int Hh) {
  __shared__ u16 As[128 * 32];
  __shared__ u16 Bs[128 * 32];
  __shared__ float sRed[2][2][128];
  const int tid = threadIdx.x;
  const int w = tid >> 6, lane = tid & 63;
  const int wm = w >> 1, wn = w & 1;
  const int q = lane >> 4, l15 = lane & 15;
  const int nBase = blockIdx.x * 128;
  const int mBase = blockIdx.y * 128;
  const int h = nBase >> 7;
  const int srow = lane >> 2;
  const int skc = (lane & 3) * 8;

  f32x4 acc[4][4];
#pragma unroll
  for (int i = 0; i < 4; ++i)
#pragma unroll
    for (int j = 0; j < 4; ++j) acc[i][j] = (f32x4){0.f, 0.f, 0.f, 0.f};

  for (int k0 = 0; k0 < K; k0 += 32) {
#pragma unroll
    for (int r = 0; r < 2; ++r) {
      int lrow = w * 32 + r * 16 + srow;
      int ga = mBase + lrow;
      if (ga >= M) ga = M - 1;
      gld_lds16(A + (size_t)ga * K + k0 + skc, &As[(w * 32 + r * 16) * 32]);
      int gb = nBase + lrow;
      gld_lds16(Bt + (size_t)gb * K + k0 + skc, &Bs[(w * 32 + r * 16) * 32]);
    }
    __syncthreads();
    short8 af[4], bf[4];
#pragma unroll
    for (int i = 0; i < 4; ++i)
      af[i] = *(const short8*)&As[(wm * 64 + i * 16 + l15) * 32 + q * 8];
#pragma unroll
    for (int j = 0; j < 4; ++j)
      bf[j] = *(const short8*)&Bs[(wn * 64 + j * 16 + l15) * 32 + q * 8];
#pragma unroll
    for (int i = 0; i < 4; ++i)
#pragma unroll
      for (int j = 0; j < 4; ++j)
        acc[i][j] = __builtin_amdgcn_mfma_f32_16x16x32_bf16(af[i], bf[j], acc[i][j], 0, 0, 0);
    __syncthreads();
  }

  float asv[4], adv[4];
#pragma unroll
  for (int j = 0; j < 4; ++j) {
    int cw = wn * 64 + j * 16 + l15;
    asv[j] = a_src[h * 128 + cw];
    adv[j] = a_dst[h * 128 + cw];
  }
#pragma unroll
  for (int mi = 0; mi < 4; ++mi) {
#pragma unroll
    for (int r = 0; r < 4; ++r) {
      int row = mBase + wm * 64 + mi * 16 + q * 4 + r;
      float s = 0.f, d = 0.f;
#pragma unroll
      for (int j = 0; j < 4; ++j) {
        float v = acc[mi][j][r];
        s = fmaf(v, asv[j], s);
        d = fmaf(v, adv[j], d);
        if (row < M) Hb[(size_t)row * HC + nBase + wn * 64 + j * 16 + l15] = f2b(v);
      }
#pragma unroll
      for (int o = 8; o; o >>= 1) {
        s += __shfl_xor(s, o);
        d += __shfl_xor(d, o);
      }
      if (l15 == 0) {
        int lr = wm * 64 + mi * 16 + q * 4 + r;
        sRed[0][wn][lr] = s;
        sRed[1][wn][lr] = d;
      }
    }
  }
  __syncthreads();
  if (tid < 128) {
    int row = mBase + tid;
    if (row < M) {
      aS[(size_t)row * Hh + h] = sRed[0][0][tid] + sRed[0][1][tid];
      aD[(size_t)row * Hh + h] = sRed[1][0][tid] + sRed[1][1][tid];
    }
  }
}

// ---------------- CSR build ----------------
__device__ inline void edge_nodes(const int* __restrict__ ei, int E0, int e, int& s, int& d) {
  if (e < E0) { s = ei[e]; d = ei[E0 + e]; }
  else        { s = e - E0; d = e - E0; }
}

__global__ void deg_count(const int* __restrict__ ei, int E0, int ET, int* __restrict__ deg) {
  int e = blockIdx.x * blockDim.x + threadIdx.x;
  if (e >= ET) return;
  int s, d;
  edge_nodes(ei, E0, e, s, d);
  atomicAdd(&deg[d], 1);
}

__global__ __launch_bounds__(256) void scan_chunk(const int* __restrict__ deg,
                                                  int* __restrict__ incl,
                                                  int* __restrict__ bsums, int N) {
  __shared__ int sdata[256];
  const int t = threadIdx.x;
  const int base = blockIdx.x * 2048;
  int v[8];
  int sum = 0;
#pragma unroll
  for (int i = 0; i < 8; ++i) {
    int idx = base + t * 8 + i;
    v[i] = (idx < N) ? deg[idx] : 0;
    sum += v[i];
  }
  sdata[t] = sum;
  __syncthreads();
  for (int off = 1; off < 256; off <<= 1) {
    int x = (t >= off) ? sdata[t - off] : 0;
    __syncthreads();
    sdata[t] += x;
    __syncthreads();
  }
  int run = (t > 0) ? sdata[t - 1] : 0;
#pragma unroll
  for (int i = 0; i < 8; ++i) {
    int idx = base + t * 8 + i;
    run += v[i];
    if (idx < N) incl[idx] = run;
  }
  if (t == 255) bsums[blockIdx.x] = sdata[255];
}

__global__ __launch_bounds__(256) void scan_bsums(int* __restrict__ bsums, int nb) {
  __shared__ int s[256];
  int t = threadIdx.x;
  s[t] = (t < nb) ? bsums[t] : 0;
  __syncthreads();
  for (int off = 1; off < 256; off <<= 1) {
    int x = (t >= off) ? s[t - off] : 0;
    __syncthreads();
    s[t] += x;
    __syncthreads();
  }
  if (t < nb) bsums[t] = (t == 0) ? 0 : s[t - 1];
}

__global__ void scan_final(const int* __restrict__ incl, const int* __restrict__ bsums,
                           int* __restrict__ rowptr, int N) {
  int i = blockIdx.x * blockDim.x + threadIdx.x;
  if (i < N) rowptr[i + 1] = incl[i] + bsums[i >> 11];
  if (i == 0) rowptr[0] = 0;
}

__global__ void csr_fill(const int* __restrict__ ei, int E0, int ET,
                         const int* __restrict__ rowptr, int* __restrict__ cnt,
                         int* __restrict__ csr_src, int* __restrict__ csr_dst) {
  int e = blockIdx.x * blockDim.x + threadIdx.x;
  if (e >= ET) return;
  int s, d;
  edge_nodes(ei, E0, e, s, d);
  int pos = atomicAdd(&cnt[d], 1);
  csr_src[rowptr[d] + pos] = s;
  csr_dst[rowptr[d] + pos] = d;
}

// ---------------- edge logits (CSR order, leaky-relu applied) ----------------
__global__ void edge_logits(const int* __restrict__ csr_src, const int* __restrict__ csr_dst,
                            const float* __restrict__ aS, const float* __restrict__ aD,
                            float* __restrict__ lbuf, int ET, int Hh) {
  int p = blockIdx.x * blockDim.x + threadIdx.x;
  if (p >= ET) return;
  int s = csr_src[p], d = csr_dst[p];
  if (Hh == 4) {
    float4 ls = *(const float4*)&aS[s * 4];
    float4 ld = *(const float4*)&aD[d * 4];
    float4 o;
    o.x = lrelu(ls.x + ld.x);
    o.y = lrelu(ls.y + ld.y);
    o.z = lrelu(ls.z + ld.z);
    o.w = lrelu(ls.w + ld.w);
    *(float4*)&lbuf[(size_t)p * 4] = o;
  } else {
    lbuf[p] = lrelu(aS[s] + aD[d]);
  }
}

// ---------------- per-node softmax stats: one wave per node ----------------
// writes msinv[node*Hh*2 + h*2] = m, [.. +1] = 1/sum
__global__ void node_softmax(const int* __restrict__ rowptr, const float* __restrict__ lbuf,
                             float* __restrict__ msinv, int N, int Hh) {
  int wid = (int)((blockIdx.x * blockDim.x + threadIdx.x) >> 6);
  int lane = threadIdx.x & 63;
  if (wid >= N) return;
  int beg = rowptr[wid], deg = rowptr[wid + 1] - beg;
  if (Hh == 4) {
    float m[4] = {-1e30f, -1e30f, -1e30f, -1e30f};
    for (int e = lane; e < deg; e += 64) {
      float4 l = *(const float4*)&lbuf[(size_t)(beg + e) * 4];
      m[0] = fmaxf(m[0], l.x);
      m[1] = fmaxf(m[1], l.y);
      m[2] = fmaxf(m[2], l.z);
      m[3] = fmaxf(m[3], l.w);
    }
#pragma unroll
    for (int o = 32; o; o >>= 1) {
#pragma unroll
      for (int i = 0; i < 4; ++i) m[i] = fmaxf(m[i], __shfl_xor(m[i], o));
    }
    float s[4] = {0.f, 0.f, 0.f, 0.f};
    for (int e = lane; e < deg; e += 64) {
      float4 l = *(const float4*)&lbuf[(size_t)(beg + e) * 4];
      s[0] += expf(l.x - m[0]);
      s[1] += expf(l.y - m[1]);
      s[2] += expf(l.z - m[2]);
      s[3] += expf(l.w - m[3]);
    }
#pragma unroll
    for (int o = 32; o; o >>= 1) {
#pragma unroll
      for (int i = 0; i < 4; ++i) s[i] += __shfl_xor(s[i], o);
    }
    if (lane == 0) {
#pragma unroll
      for (int i = 0; i < 4; ++i) {
        msinv[wid * 8 + i * 2] = m[i];
        msinv[wid * 8 + i * 2 + 1] = 1.f / s[i];
      }
    }
  } else {
    float m = -1e30f;
    for (int e = lane; e < deg; e += 64) m = fmaxf(m, lbuf[beg + e]);
#pragma unroll
    for (int o = 32; o; o >>= 1) m = fmaxf(m, __shfl_xor(m, o));
    float s = 0.f;
    for (int e = lane; e < deg; e += 64) s += expf(lbuf[beg + e] - m);
#pragma unroll
    for (int o = 32; o; o >>= 1) s += __shfl_xor(s, o);
    if (lane == 0) {
      msinv[wid * 2] = m;
      msinv[wid * 2 + 1] = 1.f / s;
    }
  }
}

// ---------------- aggregate: alpha from lbuf/msinv + bf16 gather + bias + ELU ----------------
__global__ __launch_bounds__(256) void gat_aggregate3(
    const int* __restrict__ rowptr, const int* __restrict__ csr_src,
    const u16* __restrict__ Hb, const float* __restrict__ lbuf,
    const float* __restrict__ msinv, const float* __restrict__ bias,
    u16* __restrict__ outB, float* __restrict__ outF, int Hh, int hshift, int HC) {
  __shared__ int sSrc[64];
  __shared__ float sAlpha[256];
  __shared__ float sMS[8];
  __shared__ float sRed[256][9];
  const int d = blockIdx.x;
  const int tid = threadIdx.x;
  const int beg = rowptr[d];
  const int deg = rowptr[d + 1] - beg;
  const int cg = HC >> 3;
  const int cslot = tid & (cg - 1);
  const int eslot = tid / cg;
  const int egN = 256 / cg;
  const int c0 = cslot * 8;
  const int h = c0 >> 7;

  if (tid < 2 * Hh) sMS[tid] = msinv[d * 2 * Hh + tid];
  __syncthreads();

  float acc[8] = {};
  for (int chunk = 0; chunk < deg; chunk += 64) {
    int ce = min(64, deg - chunk);
    if (tid < ce) sSrc[tid] = csr_src[beg + chunk + tid];
    for (int idx = tid; idx < (ce << hshift); idx += 256) {
      int e = idx >> hshift;
      int hh = idx & (Hh - 1);
      float l = lbuf[(size_t)(beg + chunk + e) * Hh + hh];
      sAlpha[idx] = expf(l - sMS[2 * hh]) * sMS[2 * hh + 1];
    }
    __syncthreads();
    for (int e = eslot; e < ce; e += egN) {
      float a = sAlpha[(e << hshift) + h];
      uint4 pv = *(const uint4*)&Hb[(size_t)sSrc[e] * HC + c0];
      acc[0] = fmaf(a, b2f((u16)(pv.x & 0xffff)), acc[0]);
      acc[1] = fmaf(a, b2f((u16)(pv.x >> 16)), acc[1]);
      acc[2] = fmaf(a, b2f((u16)(pv.y & 0xffff)), acc[2]);
      acc[3] = fmaf(a, b2f((u16)(pv.y >> 16)), acc[3]);
      acc[4] = fmaf(a, b2f((u16)(pv.z & 0xffff)), acc[4]);
      acc[5] = fmaf(a, b2f((u16)(pv.z >> 16)), acc[5]);
      acc[6] = fmaf(a, b2f((u16)(pv.w & 0xffff)), acc[6]);
      acc[7] = fmaf(a, b2f((u16)(pv.w >> 16)), acc[7]);
    }
    __syncthreads();
  }
#pragma unroll
  for (int i = 0; i < 8; ++i) sRed[tid][i] = acc[i];
  __syncthreads();
  if (tid < cg) {
    float tot[8];
#pragma unroll
    for (int i = 0; i < 8; ++i) tot[i] = sRed[tid][i];
    for (int e = 1; e < egN; ++e)
#pragma unroll
      for (int i = 0; i < 8; ++i) tot[i] += sRed[e * cg + tid][i];
    u16 packed[8];
#pragma unroll
    for (int i = 0; i < 8; ++i) {
      float v = tot[i] + bias[c0 + i];
      v = v > 0.f ? v : expm1f(v);
      tot[i] = v;
      packed[i] = f2b(v);
    }
    if (outB) *(uint4*)&outB[(size_t)d * HC + c0] = *(const uint4*)packed;
    if (outF) {
      *(float4*)&outF[(size_t)d * HC + c0] = make_float4(tot[0], tot[1], tot[2], tot[3]);
      *(float4*)&outF[(size_t)d * HC + c0 + 4] = make_float4(tot[4], tot[5], tot[6], tot[7]);
    }
  }
}

// ---------------- FC head (f32, tiny) ----------------
__global__ __launch_bounds__(256) void gemm_f32(const float* __restrict__ A,
                                                const float* __restrict__ B,
                                                float* __restrict__ C,
                                                int M, int N, int K) {
  __shared__ float As[16][64];
  __shared__ float Bs[16][64];
  const int tid = threadIdx.x;
  const int tx = tid & 15, ty = tid >> 4;
  const int nBase = blockIdx.x * 64;
  const int mBase = blockIdx.y * 64;
  const int aRow = tid >> 2;
  const int aK = (tid & 3) << 2;
  const int bC = tid & 63;
  const int bR0 = tid >> 6;
  float acc[4][4] = {};
  for (int k0 = 0; k0 < K; k0 += 16) {
    float4 av = make_float4(0.f, 0.f, 0.f, 0.f);
    int gr = mBase + aRow;
    if (gr < M) av = *(const float4*)&A[(size_t)gr * K + k0 + aK];
    As[aK + 0][aRow] = av.x;
    As[aK + 1][aRow] = av.y;
    As[aK + 2][aRow] = av.z;
    As[aK + 3][aRow] = av.w;
#pragma unroll
    for (int i = 0; i < 4; ++i) {
      int r = bR0 + i * 4;
      Bs[r][bC] = B[(size_t)(k0 + r) * N + nBase + bC];
    }
    __syncthreads();
#pragma unroll
    for (int k = 0; k < 16; ++k) {
      float4 a = *(const float4*)&As[k][ty * 4];
      float4 b = *(const float4*)&Bs[k][tx * 4];
      float ar[4] = {a.x, a.y, a.z, a.w};
      float br[4] = {b.x, b.y, b.z, b.w};
#pragma unroll
      for (int i = 0; i < 4; ++i)
#pragma unroll
        for (int j = 0; j < 4; ++j) acc[i][j] = fmaf(ar[i], br[j], acc[i][j]);
    }
    __syncthreads();
  }
#pragma unroll
  for (int i = 0; i < 4; ++i) {
    int gr = mBase + ty * 4 + i;
    if (gr < M)
      *(float4*)&C[(size_t)gr * N + nBase + tx * 4] =
          make_float4(acc[i][0], acc[i][1], acc[i][2], acc[i][3]);
  }
}

__global__ void bias_relu(float* __restrict__ x, const float* __restrict__ b, int total,
                          int HC) {
  int i = blockIdx.x * blockDim.x + threadIdx.x;
  if (i >= total) return;
  float v = x[i] + b[i % HC];
  x[i] = v > 0.f ? v : 0.f;
}

__global__ void fc2_sigmoid(const float* __restrict__ Hin, const float* __restrict__ w,
                            const float* __restrict__ b, float* __restrict__ out, int N) {
  int wid = (int)((blockIdx.x * blockDim.x + threadIdx.x) >> 6);
  int lane = threadIdx.x & 63;
  if (wid >= N) return;
  float v = Hin[(size_t)wid * 64 + lane] * w[lane];
#pragma unroll
  for (int o = 32; o; o >>= 1) v += __shfl_down(v, o);
  if (lane == 0) out[wid] = 1.f / (1.f + expf(-(v + b[0])));
}

// ---------------- launch ----------------
extern "C" void kernel_launch(void* const* d_in, const int* in_sizes, int n_in,
                              void* d_out, int out_size, void* d_ws, size_t ws_size,
                              hipStream_t stream) {
  const float* x    = (const float*)d_in[0];
  const int*   ei   = (const int*)d_in[1];
  const float* W1   = (const float*)d_in[2];
  const float* as1  = (const float*)d_in[3];
  const float* ad1  = (const float*)d_in[4];
  const float* b1   = (const float*)d_in[5];
  const float* W2   = (const float*)d_in[6];
  const float* as2  = (const float*)d_in[7];
  const float* ad2  = (const float*)d_in[8];
  const float* b2   = (const float*)d_in[9];
  const float* W3   = (const float*)d_in[10];
  const float* as3  = (const float*)d_in[11];
  const float* ad3  = (const float*)d_in[12];
  const float* b3   = (const float*)d_in[13];
  const float* fc1w = (const float*)d_in[14];
  const float* fc1b = (const float*)d_in[15];
  const float* fc2w = (const float*)d_in[16];
  const float* fc2b = (const float*)d_in[17];
  float* out = (float*)d_out;

  const int N  = in_sizes[0] / 64;  // 50000
  const int E0 = in_sizes[1] / 2;   // 400000
  const int ET = E0 + N;

  char* ws = (char*)d_ws;
  size_t off = 0;
  auto alloc = [&](size_t bytes) -> void* {
    void* p = ws + off;
    off += (bytes + 255) & ~(size_t)255;
    return p;
  };
  u16*   bufXb   = (u16*)alloc((size_t)N * 512 * 2);
  u16*   bufHb   = (u16*)alloc((size_t)N * 512 * 2);
  float* bufF    = (float*)alloc((size_t)N * 128 * 4);
  float* bufF2   = (float*)alloc((size_t)N * 64 * 4);
  float* aS      = (float*)alloc((size_t)N * 4 * 4);
  float* aD      = (float*)alloc((size_t)N * 4 * 4);
  float* lbuf    = (float*)alloc((size_t)ET * 4 * 4);
  float* msinv   = (float*)alloc((size_t)N * 8 * 4);
  u16*   Wt1     = (u16*)alloc((size_t)512 * 64 * 2);
  u16*   Wt2     = (u16*)alloc((size_t)512 * 512 * 2);
  u16*   Wt3     = (u16*)alloc((size_t)128 * 512 * 2);
  int*   deg     = (int*)alloc((size_t)N * 4);
  int*   cnt     = (int*)alloc((size_t)N * 4);
  int*   incl    = (int*)alloc((size_t)N * 4);
  int*   rowptr  = (int*)alloc((size_t)(N + 1) * 4);
  int*   bsums   = (int*)alloc(256 * 4);
  int*   csr_src = (int*)alloc((size_t)ET * 4);
  int*   csr_dst = (int*)alloc((size_t)ET * 4);
  (void)ws_size; (void)n_in; (void)out_size;

  // ---- upfront casts ----
  hipLaunchKernelGGL(cast_f32_bf16, dim3((N * 64 + 255) / 256), dim3(256), 0, stream, x,
                     bufXb, N * 64);
  hipLaunchKernelGGL(cast_transpose_w, dim3((64 * 512 + 255) / 256), dim3(256), 0, stream,
                     W1, Wt1, 64, 512);
  hipLaunchKernelGGL(cast_transpose_w, dim3((512 * 512 + 255) / 256), dim3(256), 0, stream,
                     W2, Wt2, 512, 512);
  hipLaunchKernelGGL(cast_transpose_w, dim3((512 * 128 + 255) / 256), dim3(256), 0, stream,
                     W3, Wt3, 512, 128);

  // ---- CSR build ----
  hipMemsetAsync(deg, 0, (size_t)N * 4, stream);
  hipMemsetAsync(cnt, 0, (size_t)N * 4, stream);
  int eb = (ET + 255) / 256;
  hipLaunchKernelGGL(deg_count, dim3(eb), dim3(256), 0, stream, ei, E0, ET, deg);
  int nb = (N + 2047) / 2048;
  hipLaunchKernelGGL(scan_chunk, dim3(nb), dim3(256), 0, stream, deg, incl, bsums, N);
  hipLaunchKernelGGL(scan_bsums, dim3(1), dim3(256), 0, stream, bsums, nb);
  hipLaunchKernelGGL(scan_final, dim3((N + 255) / 256), dim3(256), 0, stream, incl, bsums,
                     rowptr, N);
  hipLaunchKernelGGL(csr_fill, dim3(eb), dim3(256), 0, stream, ei, E0, ET, rowptr, cnt,
                     csr_src, csr_dst);

  const int gy = (N + 127) / 128;
  auto gat_layer = [&](int K, const u16* Wt, const float* a_s, const float* a_d,
                       const float* bias, int Hh, u16* aggB, float* aggF) {
    const int HC = Hh * 128;
    const int hshift = (Hh == 4) ? 2 : 0;
    hipLaunchKernelGGL(gemm_bf16_gat, dim3(HC / 128, gy), dim3(256), 0, stream, bufXb, Wt,
                       bufHb, a_s, a_d, aS, aD, N, HC, K, Hh);
    hipLaunchKernelGGL(edge_logits, dim3(eb), dim3(256), 0, stream, csr_src, csr_dst, aS,
                       aD, lbuf, ET, Hh);
    hipLaunchKernelGGL(node_softmax, dim3((N + 3) / 4), dim3(256), 0, stream, rowptr, lbuf,
                       msinv, N, Hh);
    hipLaunchKernelGGL(gat_aggregate3, dim3(N), dim3(256), 0, stream, rowptr, csr_src,
                       bufHb, lbuf, msinv, bias, aggB, aggF, Hh, hshift, HC);
  };

  gat_layer(64,  Wt1, as1, ad1, b1, 4, bufXb, nullptr);
  gat_layer(512, Wt2, as2, ad2, b2, 4, bufXb, nullptr);
  gat_layer(512, Wt3, as3, ad3, b3, 1, nullptr, bufF);

  hipLaunchKernelGGL(gemm_f32, dim3(1, (N + 63) / 64), dim3(256), 0, stream, bufF, fc1w,
                     bufF2, N, 64, 128);
  hipLaunchKernelGGL(bias_relu, dim3((N * 64 + 255) / 256), dim3(256), 0, stream, bufF2,
                     fc1b, N * 64, 64);
  hipLaunchKernelGGL(fc2_sigmoid, dim3((N + 3) / 4), dim3(256), 0, stream, bufF2, fc2w,
                     fc2b, out, N);
}

// Round 5
// 582.745 us; speedup vs baseline: 4.8370x; 1.1732x over previous
//
#include <hip/hip_runtime.h>
#include <math.h>

typedef __attribute__((ext_vector_type(8))) short short8;
typedef __attribute__((ext_vector_type(4))) float f32x4;
typedef unsigned short u16;
typedef unsigned int u32;

__device__ inline u16 f2b(float f) {  // f32 -> bf16 round-to-nearest-even
  u32 u = __float_as_uint(f);
  return (u16)((u + 0x7FFFu + ((u >> 16) & 1u)) >> 16);
}
__device__ inline float b2f(u16 b) { return __uint_as_float((u32)b << 16); }
__device__ inline float lrelu(float v) { return v > 0.f ? v : 0.2f * v; }

__device__ inline void gld_lds16(const void* g, void* l) {
  __builtin_amdgcn_global_load_lds((const __attribute__((address_space(1))) void*)g,
                                   (__attribute__((address_space(3))) void*)l, 16, 0, 0);
}

// ---------------- casts ----------------
__global__ void cast_f32_bf16(const float* __restrict__ src, u16* __restrict__ dst, int n) {
  int i = blockIdx.x * blockDim.x + threadIdx.x;
  if (i < n) dst[i] = f2b(src[i]);
}

// W [K,HC] f32 -> Wt [HC,K] bf16
__global__ void cast_transpose_w(const float* __restrict__ W, u16* __restrict__ Wt, int K,
                                 int HC) {
  int i = blockIdx.x * blockDim.x + threadIdx.x;
  if (i >= K * HC) return;
  int k = i / HC, n = i % HC;
  Wt[(size_t)n * K + k] = f2b(W[i]);
}

// ---------------- bf16 MFMA GEMM with fused alpha epilogue ----------------
__global__ __launch_bounds__(256) void gemm_bf16_gat(
    const u16* __restrict__ A, const u16* __restrict__ Bt, u16* __restrict__ Hb,
    const float* __restrict__ a_src, const float* __restrict__ a_dst,
    float* __restrict__ aS, float* __restrict__ aD, int M, int HC, int K, int Hh) {
  __shared__ u16 As[128 * 32];
  __shared__ u16 Bs[128 * 32];
  __shared__ float sRed[2][2][128];
  const int tid = threadIdx.x;
  const int w = tid >> 6, lane = tid & 63;
  const int wm = w >> 1, wn = w & 1;
  const int q = lane >> 4, l15 = lane & 15;
  const int nBase = blockIdx.x * 128;
  const int mBase = blockIdx.y * 128;
  const int h = nBase >> 7;
  const int srow = lane >> 2;
  const int skc = (lane & 3) * 8;

  f32x4 acc[4][4];
#pragma unroll
  for (int i = 0; i < 4; ++i)
#pragma unroll
    for (int j = 0; j < 4; ++j) acc[i][j] = (f32x4){0.f, 0.f, 0.f, 0.f};

  for (int k0 = 0; k0 < K; k0 += 32) {
#pragma unroll
    for (int r = 0; r < 2; ++r) {
      int lrow = w * 32 + r * 16 + srow;
      int ga = mBase + lrow;
      if (ga >= M) ga = M - 1;
      gld_lds16(A + (size_t)ga * K + k0 + skc, &As[(w * 32 + r * 16) * 32]);
      int gb = nBase + lrow;
      gld_lds16(Bt + (size_t)gb * K + k0 + skc, &Bs[(w * 32 + r * 16) * 32]);
    }
    __syncthreads();
    short8 af[4], bf[4];
#pragma unroll
    for (int i = 0; i < 4; ++i)
      af[i] = *(const short8*)&As[(wm * 64 + i * 16 + l15) * 32 + q * 8];
#pragma unroll
    for (int j = 0; j < 4; ++j)
      bf[j] = *(const short8*)&Bs[(wn * 64 + j * 16 + l15) * 32 + q * 8];
#pragma unroll
    for (int i = 0; i < 4; ++i)
#pragma unroll
      for (int j = 0; j < 4; ++j)
        acc[i][j] = __builtin_amdgcn_mfma_f32_16x16x32_bf16(af[i], bf[j], acc[i][j], 0, 0, 0);
    __syncthreads();
  }

  float asv[4], adv[4];
#pragma unroll
  for (int j = 0; j < 4; ++j) {
    int cw = wn * 64 + j * 16 + l15;
    asv[j] = a_src[h * 128 + cw];
    adv[j] = a_dst[h * 128 + cw];
  }
#pragma unroll
  for (int mi = 0; mi < 4; ++mi) {
#pragma unroll
    for (int r = 0; r < 4; ++r) {
      int row = mBase + wm * 64 + mi * 16 + q * 4 + r;
      float s = 0.f, d = 0.f;
#pragma unroll
      for (int j = 0; j < 4; ++j) {
        float v = acc[mi][j][r];
        s = fmaf(v, asv[j], s);
        d = fmaf(v, adv[j], d);
        if (row < M) Hb[(size_t)row * HC + nBase + wn * 64 + j * 16 + l15] = f2b(v);
      }
#pragma unroll
      for (int o = 8; o; o >>= 1) {
        s += __shfl_xor(s, o);
        d += __shfl_xor(d, o);
      }
      if (l15 == 0) {
        int lr = wm * 64 + mi * 16 + q * 4 + r;
        sRed[0][wn][lr] = s;
        sRed[1][wn][lr] = d;
      }
    }
  }
  __syncthreads();
  if (tid < 128) {
    int row = mBase + tid;
    if (row < M) {
      aS[(size_t)row * Hh + h] = sRed[0][0][tid] + sRed[0][1][tid];
      aD[(size_t)row * Hh + h] = sRed[1][0][tid] + sRed[1][1][tid];
    }
  }
}

// ---------------- CSR build ----------------
__device__ inline void edge_nodes(const int* __restrict__ ei, int E0, int e, int& s, int& d) {
  if (e < E0) { s = ei[e]; d = ei[E0 + e]; }
  else        { s = e - E0; d = e - E0; }
}

__global__ void deg_count(const int* __restrict__ ei, int E0, int ET, int* __restrict__ deg) {
  int e = blockIdx.x * blockDim.x + threadIdx.x;
  if (e >= ET) return;
  int s, d;
  edge_nodes(ei, E0, e, s, d);
  atomicAdd(&deg[d], 1);
}

__global__ __launch_bounds__(256) void scan_chunk(const int* __restrict__ deg,
                                                  int* __restrict__ incl,
                                                  int* __restrict__ bsums, int N) {
  __shared__ int sdata[256];
  const int t = threadIdx.x;
  const int base = blockIdx.x * 2048;
  int v[8];
  int sum = 0;
#pragma unroll
  for (int i = 0; i < 8; ++i) {
    int idx = base + t * 8 + i;
    v[i] = (idx < N) ? deg[idx] : 0;
    sum += v[i];
  }
  sdata[t] = sum;
  __syncthreads();
  for (int off = 1; off < 256; off <<= 1) {
    int x = (t >= off) ? sdata[t - off] : 0;
    __syncthreads();
    sdata[t] += x;
    __syncthreads();
  }
  int run = (t > 0) ? sdata[t - 1] : 0;
#pragma unroll
  for (int i = 0; i < 8; ++i) {
    int idx = base + t * 8 + i;
    run += v[i];
    if (idx < N) incl[idx] = run;
  }
  if (t == 255) bsums[blockIdx.x] = sdata[255];
}

__global__ __launch_bounds__(256) void scan_bsums(int* __restrict__ bsums, int nb) {
  __shared__ int s[256];
  int t = threadIdx.x;
  s[t] = (t < nb) ? bsums[t] : 0;
  __syncthreads();
  for (int off = 1; off < 256; off <<= 1) {
    int x = (t >= off) ? s[t - off] : 0;
    __syncthreads();
    s[t] += x;
    __syncthreads();
  }
  if (t < nb) bsums[t] = (t == 0) ? 0 : s[t - 1];
}

__global__ void scan_final(const int* __restrict__ incl, const int* __restrict__ bsums,
                           int* __restrict__ rowptr, int N) {
  int i = blockIdx.x * blockDim.x + threadIdx.x;
  if (i < N) rowptr[i + 1] = incl[i] + bsums[i >> 11];
  if (i == 0) rowptr[0] = 0;
}

__global__ void csr_fill(const int* __restrict__ ei, int E0, int ET,
                         const int* __restrict__ rowptr, int* __restrict__ cnt,
                         int* __restrict__ csr_src, int* __restrict__ csr_dst) {
  int e = blockIdx.x * blockDim.x + threadIdx.x;
  if (e >= ET) return;
  int s, d;
  edge_nodes(ei, E0, e, s, d);
  int pos = atomicAdd(&cnt[d], 1);
  csr_src[rowptr[d] + pos] = s;
  csr_dst[rowptr[d] + pos] = d;
}

// ---------------- edge logits (CSR order, leaky-relu applied) ----------------
__global__ void edge_logits(const int* __restrict__ csr_src, const int* __restrict__ csr_dst,
                            const float* __restrict__ aS, const float* __restrict__ aD,
                            float* __restrict__ lbuf, int ET, int Hh) {
  int p = blockIdx.x * blockDim.x + threadIdx.x;
  if (p >= ET) return;
  int s = csr_src[p], d = csr_dst[p];
  if (Hh == 4) {
    float4 ls = *(const float4*)&aS[s * 4];
    float4 ld = *(const float4*)&aD[d * 4];
    float4 o;
    o.x = lrelu(ls.x + ld.x);
    o.y = lrelu(ls.y + ld.y);
    o.z = lrelu(ls.z + ld.z);
    o.w = lrelu(ls.w + ld.w);
    *(float4*)&lbuf[(size_t)p * 4] = o;
  } else {
    lbuf[p] = lrelu(aS[s] + aD[d]);
  }
}

// ---------------- per-node softmax stats: one wave per node ----------------
__global__ void node_softmax(const int* __restrict__ rowptr, const float* __restrict__ lbuf,
                             float* __restrict__ msinv, int N, int Hh) {
  int wid = (int)((blockIdx.x * blockDim.x + threadIdx.x) >> 6);
  int lane = threadIdx.x & 63;
  if (wid >= N) return;
  int beg = rowptr[wid], deg = rowptr[wid + 1] - beg;
  if (Hh == 4) {
    float m[4] = {-1e30f, -1e30f, -1e30f, -1e30f};
    for (int e = lane; e < deg; e += 64) {
      float4 l = *(const float4*)&lbuf[(size_t)(beg + e) * 4];
      m[0] = fmaxf(m[0], l.x);
      m[1] = fmaxf(m[1], l.y);
      m[2] = fmaxf(m[2], l.z);
      m[3] = fmaxf(m[3], l.w);
    }
#pragma unroll
    for (int o = 32; o; o >>= 1) {
#pragma unroll
      for (int i = 0; i < 4; ++i) m[i] = fmaxf(m[i], __shfl_xor(m[i], o));
    }
    float s[4] = {0.f, 0.f, 0.f, 0.f};
    for (int e = lane; e < deg; e += 64) {
      float4 l = *(const float4*)&lbuf[(size_t)(beg + e) * 4];
      s[0] += expf(l.x - m[0]);
      s[1] += expf(l.y - m[1]);
      s[2] += expf(l.z - m[2]);
      s[3] += expf(l.w - m[3]);
    }
#pragma unroll
    for (int o = 32; o; o >>= 1) {
#pragma unroll
      for (int i = 0; i < 4; ++i) s[i] += __shfl_xor(s[i], o);
    }
    if (lane == 0) {
#pragma unroll
      for (int i = 0; i < 4; ++i) {
        msinv[wid * 8 + i * 2] = m[i];
        msinv[wid * 8 + i * 2 + 1] = 1.f / s[i];
      }
    }
  } else {
    float m = -1e30f;
    for (int e = lane; e < deg; e += 64) m = fmaxf(m, lbuf[beg + e]);
#pragma unroll
    for (int o = 32; o; o >>= 1) m = fmaxf(m, __shfl_xor(m, o));
    float s = 0.f;
    for (int e = lane; e < deg; e += 64) s += expf(lbuf[beg + e] - m);
#pragma unroll
    for (int o = 32; o; o >>= 1) s += __shfl_xor(s, o);
    if (lane == 0) {
      msinv[wid * 2] = m;
      msinv[wid * 2 + 1] = 1.f / s;
    }
  }
}

// ---------------- aggregate v4: ONE WAVE PER NODE, no LDS, no syncthreads ----------------
// Hh=4: lane covers 8 channels (16B bf16) of the 512-ch row; wave = full row.
// Hh=1: lane covers 2 channels (4B) of the 128-ch row.
__global__ __launch_bounds__(256) void gat_aggregate4(
    const int* __restrict__ rowptr, const int* __restrict__ csr_src,
    const u16* __restrict__ Hb, const float* __restrict__ lbuf,
    const float* __restrict__ msinv, const float* __restrict__ bias,
    u16* __restrict__ outB, float* __restrict__ outF, int N, int Hh) {
  const int wid = (int)((blockIdx.x * (blockDim.x >> 6)) + (threadIdx.x >> 6));
  const int lane = threadIdx.x & 63;
  if (wid >= N) return;
  const int beg = rowptr[wid];
  const int end = rowptr[wid + 1];

  if (Hh == 4) {
    const int c0 = lane * 8;     // 0..504
    const int h = lane >> 4;     // c0>>7
    const float m = msinv[wid * 8 + h * 2];
    const float sinv = msinv[wid * 8 + h * 2 + 1];
    float bv[8];
    *(float4*)&bv[0] = *(const float4*)&bias[c0];
    *(float4*)&bv[4] = *(const float4*)&bias[c0 + 4];
    float acc[8] = {};
    for (int p = beg; p < end; ++p) {
      int s = csr_src[p];
      float a = expf(lbuf[(size_t)p * 4 + h] - m) * sinv;
      uint4 pv = *(const uint4*)&Hb[(size_t)s * 512 + c0];
      acc[0] = fmaf(a, b2f((u16)(pv.x & 0xffff)), acc[0]);
      acc[1] = fmaf(a, b2f((u16)(pv.x >> 16)), acc[1]);
      acc[2] = fmaf(a, b2f((u16)(pv.y & 0xffff)), acc[2]);
      acc[3] = fmaf(a, b2f((u16)(pv.y >> 16)), acc[3]);
      acc[4] = fmaf(a, b2f((u16)(pv.z & 0xffff)), acc[4]);
      acc[5] = fmaf(a, b2f((u16)(pv.z >> 16)), acc[5]);
      acc[6] = fmaf(a, b2f((u16)(pv.w & 0xffff)), acc[6]);
      acc[7] = fmaf(a, b2f((u16)(pv.w >> 16)), acc[7]);
    }
    u16 packed[8];
#pragma unroll
    for (int i = 0; i < 8; ++i) {
      float v = acc[i] + bv[i];
      v = v > 0.f ? v : expm1f(v);
      acc[i] = v;
      packed[i] = f2b(v);
    }
    if (outB) *(uint4*)&outB[(size_t)wid * 512 + c0] = *(const uint4*)packed;
    if (outF) {
      *(float4*)&outF[(size_t)wid * 512 + c0] = make_float4(acc[0], acc[1], acc[2], acc[3]);
      *(float4*)&outF[(size_t)wid * 512 + c0 + 4] =
          make_float4(acc[4], acc[5], acc[6], acc[7]);
    }
  } else {
    const int c0 = lane * 2;     // 0..126
    const float m = msinv[wid * 2];
    const float sinv = msinv[wid * 2 + 1];
    const float bv0 = bias[c0], bv1 = bias[c0 + 1];
    float a0 = 0.f, a1 = 0.f;
    for (int p = beg; p < end; ++p) {
      int s = csr_src[p];
      float a = expf(lbuf[p] - m) * sinv;
      u32 pv = *(const u32*)&Hb[(size_t)s * 128 + c0];
      a0 = fmaf(a, b2f((u16)(pv & 0xffff)), a0);
      a1 = fmaf(a, b2f((u16)(pv >> 16)), a1);
    }
    float v0 = a0 + bv0, v1 = a1 + bv1;
    v0 = v0 > 0.f ? v0 : expm1f(v0);
    v1 = v1 > 0.f ? v1 : expm1f(v1);
    if (outB) {
      u16 pk[2] = {f2b(v0), f2b(v1)};
      *(u32*)&outB[(size_t)wid * 128 + c0] = *(const u32*)pk;
    }
    if (outF) *(float2*)&outF[(size_t)wid * 128 + c0] = make_float2(v0, v1);
  }
}

// ---------------- FC head (f32, fused bias+ReLU epilogue) ----------------
__global__ __launch_bounds__(256) void gemm_f32(const float* __restrict__ A,
                                                const float* __restrict__ B,
                                                const float* __restrict__ bias,
                                                float* __restrict__ C,
                                                int M, int N, int K) {
  __shared__ float As[16][64];
  __shared__ float Bs[16][64];
  const int tid = threadIdx.x;
  const int tx = tid & 15, ty = tid >> 4;
  const int nBase = blockIdx.x * 64;
  const int mBase = blockIdx.y * 64;
  const int aRow = tid >> 2;
  const int aK = (tid & 3) << 2;
  const int bC = tid & 63;
  const int bR0 = tid >> 6;
  float acc[4][4] = {};
  for (int k0 = 0; k0 < K; k0 += 16) {
    float4 av = make_float4(0.f, 0.f, 0.f, 0.f);
    int gr = mBase + aRow;
    if (gr < M) av = *(const float4*)&A[(size_t)gr * K + k0 + aK];
    As[aK + 0][aRow] = av.x;
    As[aK + 1][aRow] = av.y;
    As[aK + 2][aRow] = av.z;
    As[aK + 3][aRow] = av.w;
#pragma unroll
    for (int i = 0; i < 4; ++i) {
      int r = bR0 + i * 4;
      Bs[r][bC] = B[(size_t)(k0 + r) * N + nBase + bC];
    }
    __syncthreads();
#pragma unroll
    for (int k = 0; k < 16; ++k) {
      float4 a = *(const float4*)&As[k][ty * 4];
      float4 b = *(const float4*)&Bs[k][tx * 4];
      float ar[4] = {a.x, a.y, a.z, a.w};
      float br[4] = {b.x, b.y, b.z, b.w};
#pragma unroll
      for (int i = 0; i < 4; ++i)
#pragma unroll
        for (int j = 0; j < 4; ++j) acc[i][j] = fmaf(ar[i], br[j], acc[i][j]);
    }
    __syncthreads();
  }
  float4 bv = *(const float4*)&bias[nBase + tx * 4];
#pragma unroll
  for (int i = 0; i < 4; ++i) {
    int gr = mBase + ty * 4 + i;
    if (gr < M) {
      float4 v = make_float4(fmaxf(acc[i][0] + bv.x, 0.f), fmaxf(acc[i][1] + bv.y, 0.f),
                             fmaxf(acc[i][2] + bv.z, 0.f), fmaxf(acc[i][3] + bv.w, 0.f));
      *(float4*)&C[(size_t)gr * N + nBase + tx * 4] = v;
    }
  }
}

__global__ void fc2_sigmoid(const float* __restrict__ Hin, const float* __restrict__ w,
                            const float* __restrict__ b, float* __restrict__ out, int N) {
  int wid = (int)((blockIdx.x * blockDim.x + threadIdx.x) >> 6);
  int lane = threadIdx.x & 63;
  if (wid >= N) return;
  float v = Hin[(size_t)wid * 64 + lane] * w[lane];
#pragma unroll
  for (int o = 32; o; o >>= 1) v += __shfl_down(v, o);
  if (lane == 0) out[wid] = 1.f / (1.f + expf(-(v + b[0])));
}

// ---------------- launch ----------------
extern "C" void kernel_launch(void* const* d_in, const int* in_sizes, int n_in,
                              void* d_out, int out_size, void* d_ws, size_t ws_size,
                              hipStream_t stream) {
  const float* x    = (const float*)d_in[0];
  const int*   ei   = (const int*)d_in[1];
  const float* W1   = (const float*)d_in[2];
  const float* as1  = (const float*)d_in[3];
  const float* ad1  = (const float*)d_in[4];
  const float* b1   = (const float*)d_in[5];
  const float* W2   = (const float*)d_in[6];
  const float* as2  = (const float*)d_in[7];
  const float* ad2  = (const float*)d_in[8];
  const float* b2   = (const float*)d_in[9];
  const float* W3   = (const float*)d_in[10];
  const float* as3  = (const float*)d_in[11];
  const float* ad3  = (const float*)d_in[12];
  const float* b3   = (const float*)d_in[13];
  const float* fc1w = (const float*)d_in[14];
  const float* fc1b = (const float*)d_in[15];
  const float* fc2w = (const float*)d_in[16];
  const float* fc2b = (const float*)d_in[17];
  float* out = (float*)d_out;

  const int N  = in_sizes[0] / 64;  // 50000
  const int E0 = in_sizes[1] / 2;   // 400000
  const int ET = E0 + N;

  char* ws = (char*)d_ws;
  size_t off = 0;
  auto alloc = [&](size_t bytes) -> void* {
    void* p = ws + off;
    off += (bytes + 255) & ~(size_t)255;
    return p;
  };
  u16*   bufXb   = (u16*)alloc((size_t)N * 512 * 2);
  u16*   bufHb   = (u16*)alloc((size_t)N * 512 * 2);
  float* bufF    = (float*)alloc((size_t)N * 128 * 4);
  float* bufF2   = (float*)alloc((size_t)N * 64 * 4);
  float* aS      = (float*)alloc((size_t)N * 4 * 4);
  float* aD      = (float*)alloc((size_t)N * 4 * 4);
  float* lbuf    = (float*)alloc((size_t)ET * 4 * 4);
  float* msinv   = (float*)alloc((size_t)N * 8 * 4);
  u16*   Wt1     = (u16*)alloc((size_t)512 * 64 * 2);
  u16*   Wt2     = (u16*)alloc((size_t)512 * 512 * 2);
  u16*   Wt3     = (u16*)alloc((size_t)128 * 512 * 2);
  int*   deg     = (int*)alloc((size_t)N * 4);
  int*   cnt     = (int*)alloc((size_t)N * 4);
  int*   incl    = (int*)alloc((size_t)N * 4);
  int*   rowptr  = (int*)alloc((size_t)(N + 1) * 4);
  int*   bsums   = (int*)alloc(256 * 4);
  int*   csr_src = (int*)alloc((size_t)ET * 4);
  int*   csr_dst = (int*)alloc((size_t)ET * 4);
  (void)ws_size; (void)n_in; (void)out_size;

  // ---- upfront casts ----
  hipLaunchKernelGGL(cast_f32_bf16, dim3((N * 64 + 255) / 256), dim3(256), 0, stream, x,
                     bufXb, N * 64);
  hipLaunchKernelGGL(cast_transpose_w, dim3((64 * 512 + 255) / 256), dim3(256), 0, stream,
                     W1, Wt1, 64, 512);
  hipLaunchKernelGGL(cast_transpose_w, dim3((512 * 512 + 255) / 256), dim3(256), 0, stream,
                     W2, Wt2, 512, 512);
  hipLaunchKernelGGL(cast_transpose_w, dim3((512 * 128 + 255) / 256), dim3(256), 0, stream,
                     W3, Wt3, 512, 128);

  // ---- CSR build ----
  hipMemsetAsync(deg, 0, (size_t)N * 4, stream);
  hipMemsetAsync(cnt, 0, (size_t)N * 4, stream);
  int eb = (ET + 255) / 256;
  hipLaunchKernelGGL(deg_count, dim3(eb), dim3(256), 0, stream, ei, E0, ET, deg);
  int nb = (N + 2047) / 2048;
  hipLaunchKernelGGL(scan_chunk, dim3(nb), dim3(256), 0, stream, deg, incl, bsums, N);
  hipLaunchKernelGGL(scan_bsums, dim3(1), dim3(256), 0, stream, bsums, nb);
  hipLaunchKernelGGL(scan_final, dim3((N + 255) / 256), dim3(256), 0, stream, incl, bsums,
                     rowptr, N);
  hipLaunchKernelGGL(csr_fill, dim3(eb), dim3(256), 0, stream, ei, E0, ET, rowptr, cnt,
                     csr_src, csr_dst);

  const int gy = (N + 127) / 128;
  auto gat_layer = [&](int K, const u16* Wt, const float* a_s, const float* a_d,
                       const float* bias, int Hh, u16* aggB, float* aggF) {
    const int HC = Hh * 128;
    hipLaunchKernelGGL(gemm_bf16_gat, dim3(HC / 128, gy), dim3(256), 0, stream, bufXb, Wt,
                       bufHb, a_s, a_d, aS, aD, N, HC, K, Hh);
    hipLaunchKernelGGL(edge_logits, dim3(eb), dim3(256), 0, stream, csr_src, csr_dst, aS,
                       aD, lbuf, ET, Hh);
    hipLaunchKernelGGL(node_softmax, dim3((N + 3) / 4), dim3(256), 0, stream, rowptr, lbuf,
                       msinv, N, Hh);
    hipLaunchKernelGGL(gat_aggregate4, dim3((N + 3) / 4), dim3(256), 0, stream, rowptr,
                       csr_src, bufHb, lbuf, msinv, bias, aggB, aggF, N, Hh);
  };

  gat_layer(64,  Wt1, as1, ad1, b1, 4, bufXb, nullptr);
  gat_layer(512, Wt2, as2, ad2, b2, 4, bufXb, nullptr);
  gat_layer(512, Wt3, as3, ad3, b3, 1, nullptr, bufF);

  hipLaunchKernelGGL(gemm_f32, dim3(1, (N + 63) / 64), dim3(256), 0, stream, bufF, fc1w,
                     fc1b, bufF2, N, 64, 128);
  hipLaunchKernelGGL(fc2_sigmoid, dim3((N + 3) / 4), dim3(256), 0, stream, bufF2, fc2w,
                     fc2b, out, N);
}

// Round 6
// 475.210 us; speedup vs baseline: 5.9315x; 1.2263x over previous
//
#include <hip/hip_runtime.h>
#include <math.h>

typedef __attribute__((ext_vector_type(8))) short short8;
typedef __attribute__((ext_vector_type(4))) float f32x4;
typedef unsigned short u16;
typedef unsigned int u32;

__device__ inline u16 f2b(float f) {  // f32 -> bf16 round-to-nearest-even
  u32 u = __float_as_uint(f);
  return (u16)((u + 0x7FFFu + ((u >> 16) & 1u)) >> 16);
}
__device__ inline float b2f(u16 b) { return __uint_as_float((u32)b << 16); }
__device__ inline float lrelu(float v) { return v > 0.f ? v : 0.2f * v; }

__device__ inline void gld_lds16(const void* g, void* l) {
  __builtin_amdgcn_global_load_lds((const __attribute__((address_space(1))) void*)g,
                                   (__attribute__((address_space(3))) void*)l, 16, 0, 0);
}

// ---------------- casts ----------------
__global__ void cast_f32_bf16(const float* __restrict__ src, u16* __restrict__ dst, int n) {
  int i = blockIdx.x * blockDim.x + threadIdx.x;
  if (i < n) dst[i] = f2b(src[i]);
}

// W [K,HC] f32 -> Wt [HC,K] bf16
__global__ void cast_transpose_w(const float* __restrict__ W, u16* __restrict__ Wt, int K,
                                 int HC) {
  int i = blockIdx.x * blockDim.x + threadIdx.x;
  if (i >= K * HC) return;
  int k = i / HC, n = i % HC;
  Wt[(size_t)n * K + k] = f2b(W[i]);
}

// ---------------- bf16 MFMA GEMM with fused alpha epilogue ----------------
__global__ __launch_bounds__(256) void gemm_bf16_gat(
    const u16* __restrict__ A, const u16* __restrict__ Bt, u16* __restrict__ Hb,
    const float* __restrict__ a_src, const float* __restrict__ a_dst,
    float* __restrict__ aS, float* __restrict__ aD, int M, int HC, int K, int Hh) {
  __shared__ u16 As[128 * 32];
  __shared__ u16 Bs[128 * 32];
  __shared__ float sRed[2][2][128];
  const int tid = threadIdx.x;
  const int w = tid >> 6, lane = tid & 63;
  const int wm = w >> 1, wn = w & 1;
  const int q = lane >> 4, l15 = lane & 15;
  const int nBase = blockIdx.x * 128;
  const int mBase = blockIdx.y * 128;
  const int h = nBase >> 7;
  const int srow = lane >> 2;
  const int skc = (lane & 3) * 8;

  f32x4 acc[4][4];
#pragma unroll
  for (int i = 0; i < 4; ++i)
#pragma unroll
    for (int j = 0; j < 4; ++j) acc[i][j] = (f32x4){0.f, 0.f, 0.f, 0.f};

  for (int k0 = 0; k0 < K; k0 += 32) {
#pragma unroll
    for (int r = 0; r < 2; ++r) {
      int lrow = w * 32 + r * 16 + srow;
      int ga = mBase + lrow;
      if (ga >= M) ga = M - 1;
      gld_lds16(A + (size_t)ga * K + k0 + skc, &As[(w * 32 + r * 16) * 32]);
      int gb = nBase + lrow;
      gld_lds16(Bt + (size_t)gb * K + k0 + skc, &Bs[(w * 32 + r * 16) * 32]);
    }
    __syncthreads();
    short8 af[4], bf[4];
#pragma unroll
    for (int i = 0; i < 4; ++i)
      af[i] = *(const short8*)&As[(wm * 64 + i * 16 + l15) * 32 + q * 8];
#pragma unroll
    for (int j = 0; j < 4; ++j)
      bf[j] = *(const short8*)&Bs[(wn * 64 + j * 16 + l15) * 32 + q * 8];
#pragma unroll
    for (int i = 0; i < 4; ++i)
#pragma unroll
      for (int j = 0; j < 4; ++j)
        acc[i][j] = __builtin_amdgcn_mfma_f32_16x16x32_bf16(af[i], bf[j], acc[i][j], 0, 0, 0);
    __syncthreads();
  }

  float asv[4], adv[4];
#pragma unroll
  for (int j = 0; j < 4; ++j) {
    int cw = wn * 64 + j * 16 + l15;
    asv[j] = a_src[h * 128 + cw];
    adv[j] = a_dst[h * 128 + cw];
  }
#pragma unroll
  for (int mi = 0; mi < 4; ++mi) {
#pragma unroll
    for (int r = 0; r < 4; ++r) {
      int row = mBase + wm * 64 + mi * 16 + q * 4 + r;
      float s = 0.f, d = 0.f;
#pragma unroll
      for (int j = 0; j < 4; ++j) {
        float v = acc[mi][j][r];
        s = fmaf(v, asv[j], s);
        d = fmaf(v, adv[j], d);
        if (row < M) Hb[(size_t)row * HC + nBase + wn * 64 + j * 16 + l15] = f2b(v);
      }
#pragma unroll
      for (int o = 8; o; o >>= 1) {
        s += __shfl_xor(s, o);
        d += __shfl_xor(d, o);
      }
      if (l15 == 0) {
        int lr = wm * 64 + mi * 16 + q * 4 + r;
        sRed[0][wn][lr] = s;
        sRed[1][wn][lr] = d;
      }
    }
  }
  __syncthreads();
  if (tid < 128) {
    int row = mBase + tid;
    if (row < M) {
      aS[(size_t)row * Hh + h] = sRed[0][0][tid] + sRed[0][1][tid];
      aD[(size_t)row * Hh + h] = sRed[1][0][tid] + sRed[1][1][tid];
    }
  }
}

// ---------------- CSR build ----------------
__device__ inline void edge_nodes(const int* __restrict__ ei, int E0, int e, int& s, int& d) {
  if (e < E0) { s = ei[e]; d = ei[E0 + e]; }
  else        { s = e - E0; d = e - E0; }
}

__global__ void deg_count(const int* __restrict__ ei, int E0, int ET, int* __restrict__ deg) {
  int e = blockIdx.x * blockDim.x + threadIdx.x;
  if (e >= ET) return;
  int s, d;
  edge_nodes(ei, E0, e, s, d);
  atomicAdd(&deg[d], 1);
}

__global__ __launch_bounds__(256) void scan_chunk(const int* __restrict__ deg,
                                                  int* __restrict__ incl,
                                                  int* __restrict__ bsums, int N) {
  __shared__ int sdata[256];
  const int t = threadIdx.x;
  const int base = blockIdx.x * 2048;
  int v[8];
  int sum = 0;
#pragma unroll
  for (int i = 0; i < 8; ++i) {
    int idx = base + t * 8 + i;
    v[i] = (idx < N) ? deg[idx] : 0;
    sum += v[i];
  }
  sdata[t] = sum;
  __syncthreads();
  for (int off = 1; off < 256; off <<= 1) {
    int x = (t >= off) ? sdata[t - off] : 0;
    __syncthreads();
    sdata[t] += x;
    __syncthreads();
  }
  int run = (t > 0) ? sdata[t - 1] : 0;
#pragma unroll
  for (int i = 0; i < 8; ++i) {
    int idx = base + t * 8 + i;
    run += v[i];
    if (idx < N) incl[idx] = run;
  }
  if (t == 255) bsums[blockIdx.x] = sdata[255];
}

__global__ __launch_bounds__(256) void scan_bsums(int* __restrict__ bsums, int nb) {
  __shared__ int s[256];
  int t = threadIdx.x;
  s[t] = (t < nb) ? bsums[t] : 0;
  __syncthreads();
  for (int off = 1; off < 256; off <<= 1) {
    int x = (t >= off) ? s[t - off] : 0;
    __syncthreads();
    s[t] += x;
    __syncthreads();
  }
  if (t < nb) bsums[t] = (t == 0) ? 0 : s[t - 1];
}

__global__ void scan_final(const int* __restrict__ incl, const int* __restrict__ bsums,
                           int* __restrict__ rowptr, int N) {
  int i = blockIdx.x * blockDim.x + threadIdx.x;
  if (i < N) rowptr[i + 1] = incl[i] + bsums[i >> 11];
  if (i == 0) rowptr[0] = 0;
}

__global__ void csr_fill(const int* __restrict__ ei, int E0, int ET,
                         const int* __restrict__ rowptr, int* __restrict__ cnt,
                         int* __restrict__ csr_src) {
  int e = blockIdx.x * blockDim.x + threadIdx.x;
  if (e >= ET) return;
  int s, d;
  edge_nodes(ei, E0, e, s, d);
  int pos = atomicAdd(&cnt[d], 1);
  csr_src[rowptr[d] + pos] = s;
}

// ---------------- fully-fused softmax + aggregate: ONE WAVE PER NODE ----------------
// Hh=4: chunks of 16 edges; lane (h*16+e) computes logit for edge e, head h.
//        Online softmax across chunks; gather: lane covers 8 ch (16B), head = lane>>4.
// Hh=1: chunks of 64 edges; lane e computes logit for edge e; lane covers 2 ch.
__global__ __launch_bounds__(256) void gat_fused_agg(
    const int* __restrict__ rowptr, const int* __restrict__ csr_src,
    const u16* __restrict__ Hb, const float* __restrict__ aSb,
    const float* __restrict__ aDb, const float* __restrict__ bias,
    u16* __restrict__ outB, float* __restrict__ outF, int N, int Hh) {
  const int wid = (int)((blockIdx.x * (blockDim.x >> 6)) + (threadIdx.x >> 6));
  const int lane = threadIdx.x & 63;
  if (wid >= N) return;
  const int beg = rowptr[wid];
  const int deg = rowptr[wid + 1] - beg;

  if (Hh == 4) {
    const int h = lane >> 4;        // softmax head AND gather head
    const int e16 = lane & 15;      // edge slot within chunk
    const int c0 = lane * 8;        // gather channels
    const float adh = aDb[(size_t)wid * 4 + h];
    float bv[8];
    *(float4*)&bv[0] = *(const float4*)&bias[c0];
    *(float4*)&bv[4] = *(const float4*)&bias[c0 + 4];
    float m = -1e30f, ssum = 0.f;
    float acc[8] = {};
    for (int c = 0; c < deg; c += 16) {
      const int ce = min(16, deg - c);
      int srcv = 0;
      float l = -1e30f;
      if (e16 < ce) {
        srcv = csr_src[beg + c + e16];
        l = lrelu(aSb[(size_t)srcv * 4 + h] + adh);
      }
      // chunk max within 16-lane head group
      float cm = l;
#pragma unroll
      for (int o = 8; o; o >>= 1) cm = fmaxf(cm, __shfl_xor(cm, o));
      float newm = fmaxf(m, cm);
      float r = expf(m - newm);
      m = newm;
      float pexp = expf(l - m);  // 0 for inactive lanes
      float cs = pexp;
#pragma unroll
      for (int o = 8; o; o >>= 1) cs += __shfl_xor(cs, o);
      ssum = ssum * r + cs;
#pragma unroll
      for (int i = 0; i < 8; ++i) acc[i] *= r;
      const int hbase = lane & 48;
      for (int e = 0; e < ce; ++e) {
        int se = __shfl(srcv, e);          // lane e holds edge e's src
        float wgt = __shfl(pexp, hbase | e);  // lane h*16+e holds (e,h) weight
        uint4 pv = *(const uint4*)&Hb[(size_t)se * 512 + c0];
        acc[0] = fmaf(wgt, b2f((u16)(pv.x & 0xffff)), acc[0]);
        acc[1] = fmaf(wgt, b2f((u16)(pv.x >> 16)), acc[1]);
        acc[2] = fmaf(wgt, b2f((u16)(pv.y & 0xffff)), acc[2]);
        acc[3] = fmaf(wgt, b2f((u16)(pv.y >> 16)), acc[3]);
        acc[4] = fmaf(wgt, b2f((u16)(pv.z & 0xffff)), acc[4]);
        acc[5] = fmaf(wgt, b2f((u16)(pv.z >> 16)), acc[5]);
        acc[6] = fmaf(wgt, b2f((u16)(pv.w & 0xffff)), acc[6]);
        acc[7] = fmaf(wgt, b2f((u16)(pv.w >> 16)), acc[7]);
      }
    }
    const float inv = 1.f / ssum;
    u16 packed[8];
#pragma unroll
    for (int i = 0; i < 8; ++i) {
      float v = fmaf(acc[i], inv, bv[i]);
      v = v > 0.f ? v : expm1f(v);
      acc[i] = v;
      packed[i] = f2b(v);
    }
    if (outB) *(uint4*)&outB[(size_t)wid * 512 + c0] = *(const uint4*)packed;
    if (outF) {
      *(float4*)&outF[(size_t)wid * 512 + c0] = make_float4(acc[0], acc[1], acc[2], acc[3]);
      *(float4*)&outF[(size_t)wid * 512 + c0 + 4] =
          make_float4(acc[4], acc[5], acc[6], acc[7]);
    }
  } else {
    const int c0 = lane * 2;
    const float adh = aDb[wid];
    const float bv0 = bias[c0], bv1 = bias[c0 + 1];
    float m = -1e30f, ssum = 0.f;
    float a0 = 0.f, a1 = 0.f;
    for (int c = 0; c < deg; c += 64) {
      const int ce = min(64, deg - c);
      int srcv = 0;
      float l = -1e30f;
      if (lane < ce) {
        srcv = csr_src[beg + c + lane];
        l = lrelu(aSb[srcv] + adh);
      }
      float cm = l;
#pragma unroll
      for (int o = 32; o; o >>= 1) cm = fmaxf(cm, __shfl_xor(cm, o));
      float newm = fmaxf(m, cm);
      float r = expf(m - newm);
      m = newm;
      float pexp = expf(l - m);
      float cs = pexp;
#pragma unroll
      for (int o = 32; o; o >>= 1) cs += __shfl_xor(cs, o);
      ssum = ssum * r + cs;
      a0 *= r;
      a1 *= r;
      for (int e = 0; e < ce; ++e) {
        int se = __shfl(srcv, e);
        float wgt = __shfl(pexp, e);
        u32 pv = *(const u32*)&Hb[(size_t)se * 128 + c0];
        a0 = fmaf(wgt, b2f((u16)(pv & 0xffff)), a0);
        a1 = fmaf(wgt, b2f((u16)(pv >> 16)), a1);
      }
    }
    const float inv = 1.f / ssum;
    float v0 = fmaf(a0, inv, bv0), v1 = fmaf(a1, inv, bv1);
    v0 = v0 > 0.f ? v0 : expm1f(v0);
    v1 = v1 > 0.f ? v1 : expm1f(v1);
    if (outB) {
      u16 pk[2] = {f2b(v0), f2b(v1)};
      *(u32*)&outB[(size_t)wid * 128 + c0] = *(const u32*)pk;
    }
    if (outF) *(float2*)&outF[(size_t)wid * 128 + c0] = make_float2(v0, v1);
  }
}

// ---------------- fused FC head: (X@fc1w + b1).relu() @ fc2w + b2 -> sigmoid ----------------
// A:[M,128] f32, fc1w:[128,64], fc2w:[64], out:[M]. 64 rows per block.
__global__ __launch_bounds__(256) void fc_head(const float* __restrict__ A,
                                               const float* __restrict__ B,
                                               const float* __restrict__ bias,
                                               const float* __restrict__ w2,
                                               const float* __restrict__ b2,
                                               float* __restrict__ out, int M) {
  __shared__ float As[16][64];
  __shared__ float Bs[16][64];
  __shared__ float sP[64][17];
  const int tid = threadIdx.x;
  const int tx = tid & 15, ty = tid >> 4;
  const int mBase = blockIdx.y * 64;
  const int aRow = tid >> 2;
  const int aK = (tid & 3) << 2;
  const int bC = tid & 63;
  const int bR0 = tid >> 6;
  const int K = 128, N = 64;
  float acc[4][4] = {};
  for (int k0 = 0; k0 < K; k0 += 16) {
    float4 av = make_float4(0.f, 0.f, 0.f, 0.f);
    int gr = mBase + aRow;
    if (gr < M) av = *(const float4*)&A[(size_t)gr * K + k0 + aK];
    As[aK + 0][aRow] = av.x;
    As[aK + 1][aRow] = av.y;
    As[aK + 2][aRow] = av.z;
    As[aK + 3][aRow] = av.w;
#pragma unroll
    for (int i = 0; i < 4; ++i) {
      int r = bR0 + i * 4;
      Bs[r][bC] = B[(size_t)(k0 + r) * N + bC];
    }
    __syncthreads();
#pragma unroll
    for (int k = 0; k < 16; ++k) {
      float4 a = *(const float4*)&As[k][ty * 4];
      float4 b = *(const float4*)&Bs[k][tx * 4];
      float ar[4] = {a.x, a.y, a.z, a.w};
      float br[4] = {b.x, b.y, b.z, b.w};
#pragma unroll
      for (int i = 0; i < 4; ++i)
#pragma unroll
        for (int j = 0; j < 4; ++j) acc[i][j] = fmaf(ar[i], br[j], acc[i][j]);
    }
    __syncthreads();
  }
  float4 bv = *(const float4*)&bias[tx * 4];
  float4 wv = *(const float4*)&w2[tx * 4];
#pragma unroll
  for (int i = 0; i < 4; ++i) {
    float p = 0.f;
    p = fmaf(fmaxf(acc[i][0] + bv.x, 0.f), wv.x, p);
    p = fmaf(fmaxf(acc[i][1] + bv.y, 0.f), wv.y, p);
    p = fmaf(fmaxf(acc[i][2] + bv.z, 0.f), wv.z, p);
    p = fmaf(fmaxf(acc[i][3] + bv.w, 0.f), wv.w, p);
    sP[ty * 4 + i][tx] = p;
  }
  __syncthreads();
  if (tid < 64) {
    int row = mBase + tid;
    if (row < M) {
      float s = 0.f;
#pragma unroll
      for (int t = 0; t < 16; ++t) s += sP[tid][t];
      out[row] = 1.f / (1.f + expf(-(s + b2[0])));
    }
  }
}

// ---------------- launch ----------------
extern "C" void kernel_launch(void* const* d_in, const int* in_sizes, int n_in,
                              void* d_out, int out_size, void* d_ws, size_t ws_size,
                              hipStream_t stream) {
  const float* x    = (const float*)d_in[0];
  const int*   ei   = (const int*)d_in[1];
  const float* W1   = (const float*)d_in[2];
  const float* as1  = (const float*)d_in[3];
  const float* ad1  = (const float*)d_in[4];
  const float* b1   = (const float*)d_in[5];
  const float* W2   = (const float*)d_in[6];
  const float* as2  = (const float*)d_in[7];
  const float* ad2  = (const float*)d_in[8];
  const float* b2   = (const float*)d_in[9];
  const float* W3   = (const float*)d_in[10];
  const float* as3  = (const float*)d_in[11];
  const float* ad3  = (const float*)d_in[12];
  const float* b3   = (const float*)d_in[13];
  const float* fc1w = (const float*)d_in[14];
  const float* fc1b = (const float*)d_in[15];
  const float* fc2w = (const float*)d_in[16];
  const float* fc2b = (const float*)d_in[17];
  float* out = (float*)d_out;

  const int N  = in_sizes[0] / 64;  // 50000
  const int E0 = in_sizes[1] / 2;   // 400000
  const int ET = E0 + N;

  char* ws = (char*)d_ws;
  size_t off = 0;
  auto alloc = [&](size_t bytes) -> void* {
    void* p = ws + off;
    off += (bytes + 255) & ~(size_t)255;
    return p;
  };
  u16*   bufXb   = (u16*)alloc((size_t)N * 512 * 2);
  u16*   bufHb   = (u16*)alloc((size_t)N * 512 * 2);
  float* bufF    = (float*)alloc((size_t)N * 128 * 4);
  float* aS      = (float*)alloc((size_t)N * 4 * 4);
  float* aD      = (float*)alloc((size_t)N * 4 * 4);
  u16*   Wt1     = (u16*)alloc((size_t)512 * 64 * 2);
  u16*   Wt2     = (u16*)alloc((size_t)512 * 512 * 2);
  u16*   Wt3     = (u16*)alloc((size_t)128 * 512 * 2);
  int*   deg     = (int*)alloc((size_t)N * 4);
  int*   cnt     = (int*)alloc((size_t)N * 4);
  int*   incl    = (int*)alloc((size_t)N * 4);
  int*   rowptr  = (int*)alloc((size_t)(N + 1) * 4);
  int*   bsums   = (int*)alloc(256 * 4);
  int*   csr_src = (int*)alloc((size_t)ET * 4);
  (void)ws_size; (void)n_in; (void)out_size;

  // ---- upfront casts ----
  hipLaunchKernelGGL(cast_f32_bf16, dim3((N * 64 + 255) / 256), dim3(256), 0, stream, x,
                     bufXb, N * 64);
  hipLaunchKernelGGL(cast_transpose_w, dim3((64 * 512 + 255) / 256), dim3(256), 0, stream,
                     W1, Wt1, 64, 512);
  hipLaunchKernelGGL(cast_transpose_w, dim3((512 * 512 + 255) / 256), dim3(256), 0, stream,
                     W2, Wt2, 512, 512);
  hipLaunchKernelGGL(cast_transpose_w, dim3((512 * 128 + 255) / 256), dim3(256), 0, stream,
                     W3, Wt3, 512, 128);

  // ---- CSR build ----
  hipMemsetAsync(deg, 0, (size_t)N * 4, stream);
  hipMemsetAsync(cnt, 0, (size_t)N * 4, stream);
  int eb = (ET + 255) / 256;
  hipLaunchKernelGGL(deg_count, dim3(eb), dim3(256), 0, stream, ei, E0, ET, deg);
  int nb = (N + 2047) / 2048;
  hipLaunchKernelGGL(scan_chunk, dim3(nb), dim3(256), 0, stream, deg, incl, bsums, N);
  hipLaunchKernelGGL(scan_bsums, dim3(1), dim3(256), 0, stream, bsums, nb);
  hipLaunchKernelGGL(scan_final, dim3((N + 255) / 256), dim3(256), 0, stream, incl, bsums,
                     rowptr, N);
  hipLaunchKernelGGL(csr_fill, dim3(eb), dim3(256), 0, stream, ei, E0, ET, rowptr, cnt,
                     csr_src);

  const int gy = (N + 127) / 128;
  auto gat_layer = [&](int K, const u16* Wt, const float* a_s, const float* a_d,
                       const float* bias, int Hh, u16* aggB, float* aggF) {
    const int HC = Hh * 128;
    hipLaunchKernelGGL(gemm_bf16_gat, dim3(HC / 128, gy), dim3(256), 0, stream, bufXb, Wt,
                       bufHb, a_s, a_d, aS, aD, N, HC, K, Hh);
    hipLaunchKernelGGL(gat_fused_agg, dim3((N + 3) / 4), dim3(256), 0, stream, rowptr,
                       csr_src, bufHb, aS, aD, bias, aggB, aggF, N, Hh);
  };

  gat_layer(64,  Wt1, as1, ad1, b1, 4, bufXb, nullptr);
  gat_layer(512, Wt2, as2, ad2, b2, 4, bufXb, nullptr);
  gat_layer(512, Wt3, as3, ad3, b3, 1, nullptr, bufF);

  hipLaunchKernelGGL(fc_head, dim3(1, (N + 63) / 64), dim3(256), 0, stream, bufF, fc1w,
                     fc1b, fc2w, fc2b, out, N);
}

// Round 7
// 463.431 us; speedup vs baseline: 6.0823x; 1.0254x over previous
//
#include <hip/hip_runtime.h>
#include <math.h>

typedef __attribute__((ext_vector_type(8))) short short8;
typedef __attribute__((ext_vector_type(4))) float f32x4;
typedef unsigned short u16;
typedef unsigned int u32;

__device__ inline u16 f2b(float f) {  // f32 -> bf16 round-to-nearest-even
  u32 u = __float_as_uint(f);
  return (u16)((u + 0x7FFFu + ((u >> 16) & 1u)) >> 16);
}
__device__ inline float b2f(u16 b) { return __uint_as_float((u32)b << 16); }
__device__ inline float lrelu(float v) { return v > 0.f ? v : 0.2f * v; }

__device__ inline void gld_lds16(const void* g, void* l) {
  __builtin_amdgcn_global_load_lds((const __attribute__((address_space(1))) void*)g,
                                   (__attribute__((address_space(3))) void*)l, 16, 0, 0);
}

// ---------------- fused prep: casts (x, W1, W2, W3) + deg_count ----------------
// ranges (elements): [0, NX) x-cast; then W1 (64*512), W2 (512*512), W3 (512*128); then ET deg.
__global__ void fused_prep(const float* __restrict__ x, u16* __restrict__ xb, int NX,
                           const float* __restrict__ W1, u16* __restrict__ Wt1,
                           const float* __restrict__ W2, u16* __restrict__ Wt2,
                           const float* __restrict__ W3, u16* __restrict__ Wt3,
                           const int* __restrict__ ei, int E0, int ET,
                           int* __restrict__ deg) {
  int i = blockIdx.x * blockDim.x + threadIdx.x;
  if (i < NX) {
    xb[i] = f2b(x[i]);
    return;
  }
  i -= NX;
  if (i < 64 * 512) {
    int k = i / 512, n = i % 512;
    Wt1[n * 64 + k] = f2b(W1[i]);
    return;
  }
  i -= 64 * 512;
  if (i < 512 * 512) {
    int k = i / 512, n = i % 512;
    Wt2[n * 512 + k] = f2b(W2[i]);
    return;
  }
  i -= 512 * 512;
  if (i < 512 * 128) {
    int k = i / 128, n = i % 128;
    Wt3[n * 512 + k] = f2b(W3[i]);
    return;
  }
  i -= 512 * 128;
  if (i < ET) {
    int d = (i < E0) ? ei[E0 + i] : (i - E0);
    atomicAdd(&deg[d], 1);
  }
}

// ---------------- bf16 MFMA GEMM with fused alpha epilogue ----------------
__global__ __launch_bounds__(256) void gemm_bf16_gat(
    const u16* __restrict__ A, const u16* __restrict__ Bt, u16* __restrict__ Hb,
    const float* __restrict__ a_src, const float* __restrict__ a_dst,
    float* __restrict__ aS, float* __restrict__ aD, int M, int HC, int K, int Hh) {
  __shared__ u16 As[128 * 32];
  __shared__ u16 Bs[128 * 32];
  __shared__ float sRed[2][2][128];
  const int tid = threadIdx.x;
  const int w = tid >> 6, lane = tid & 63;
  const int wm = w >> 1, wn = w & 1;
  const int q = lane >> 4, l15 = lane & 15;
  const int nBase = blockIdx.x * 128;
  const int mBase = blockIdx.y * 128;
  const int h = nBase >> 7;
  const int srow = lane >> 2;
  const int skc = (lane & 3) * 8;

  f32x4 acc[4][4];
#pragma unroll
  for (int i = 0; i < 4; ++i)
#pragma unroll
    for (int j = 0; j < 4; ++j) acc[i][j] = (f32x4){0.f, 0.f, 0.f, 0.f};

  for (int k0 = 0; k0 < K; k0 += 32) {
#pragma unroll
    for (int r = 0; r < 2; ++r) {
      int lrow = w * 32 + r * 16 + srow;
      int ga = mBase + lrow;
      if (ga >= M) ga = M - 1;
      gld_lds16(A + (size_t)ga * K + k0 + skc, &As[(w * 32 + r * 16) * 32]);
      int gb = nBase + lrow;
      gld_lds16(Bt + (size_t)gb * K + k0 + skc, &Bs[(w * 32 + r * 16) * 32]);
    }
    __syncthreads();
    short8 af[4], bf[4];
#pragma unroll
    for (int i = 0; i < 4; ++i)
      af[i] = *(const short8*)&As[(wm * 64 + i * 16 + l15) * 32 + q * 8];
#pragma unroll
    for (int j = 0; j < 4; ++j)
      bf[j] = *(const short8*)&Bs[(wn * 64 + j * 16 + l15) * 32 + q * 8];
#pragma unroll
    for (int i = 0; i < 4; ++i)
#pragma unroll
      for (int j = 0; j < 4; ++j)
        acc[i][j] = __builtin_amdgcn_mfma_f32_16x16x32_bf16(af[i], bf[j], acc[i][j], 0, 0, 0);
    __syncthreads();
  }

  float asv[4], adv[4];
#pragma unroll
  for (int j = 0; j < 4; ++j) {
    int cw = wn * 64 + j * 16 + l15;
    asv[j] = a_src[h * 128 + cw];
    adv[j] = a_dst[h * 128 + cw];
  }
#pragma unroll
  for (int mi = 0; mi < 4; ++mi) {
#pragma unroll
    for (int r = 0; r < 4; ++r) {
      int row = mBase + wm * 64 + mi * 16 + q * 4 + r;
      float s = 0.f, d = 0.f;
#pragma unroll
      for (int j = 0; j < 4; ++j) {
        float v = acc[mi][j][r];
        s = fmaf(v, asv[j], s);
        d = fmaf(v, adv[j], d);
        if (row < M) Hb[(size_t)row * HC + nBase + wn * 64 + j * 16 + l15] = f2b(v);
      }
#pragma unroll
      for (int o = 8; o; o >>= 1) {
        s += __shfl_xor(s, o);
        d += __shfl_xor(d, o);
      }
      if (l15 == 0) {
        int lr = wm * 64 + mi * 16 + q * 4 + r;
        sRed[0][wn][lr] = s;
        sRed[1][wn][lr] = d;
      }
    }
  }
  __syncthreads();
  if (tid < 128) {
    int row = mBase + tid;
    if (row < M) {
      aS[(size_t)row * Hh + h] = sRed[0][0][tid] + sRed[0][1][tid];
      aD[(size_t)row * Hh + h] = sRed[1][0][tid] + sRed[1][1][tid];
    }
  }
}

// ---------------- CSR scan ----------------
__global__ __launch_bounds__(256) void scan_chunk(const int* __restrict__ deg,
                                                  int* __restrict__ incl,
                                                  int* __restrict__ bsums, int N) {
  __shared__ int sdata[256];
  const int t = threadIdx.x;
  const int base = blockIdx.x * 2048;
  int v[8];
  int sum = 0;
#pragma unroll
  for (int i = 0; i < 8; ++i) {
    int idx = base + t * 8 + i;
    v[i] = (idx < N) ? deg[idx] : 0;
    sum += v[i];
  }
  sdata[t] = sum;
  __syncthreads();
  for (int off = 1; off < 256; off <<= 1) {
    int x = (t >= off) ? sdata[t - off] : 0;
    __syncthreads();
    sdata[t] += x;
    __syncthreads();
  }
  int run = (t > 0) ? sdata[t - 1] : 0;
#pragma unroll
  for (int i = 0; i < 8; ++i) {
    int idx = base + t * 8 + i;
    run += v[i];
    if (idx < N) incl[idx] = run;
  }
  if (t == 255) bsums[blockIdx.x] = sdata[255];
}

// rowptr[i+1] = incl[i] + exclusive_prefix(bsums)[i>>11]; rowptr[0]=0.
__global__ void scan_final(const int* __restrict__ incl, const int* __restrict__ bsums,
                           int* __restrict__ rowptr, int N, int nb) {
  int i = blockIdx.x * blockDim.x + threadIdx.x;
  if (i >= N) return;
  int chunk = i >> 11;
  int pre = 0;
  for (int j = 0; j < chunk; ++j) pre += bsums[j];  // nb<=25, redundant but cheap
  rowptr[i + 1] = incl[i] + pre;
  if (i == 0) rowptr[0] = 0;
}

__global__ void csr_fill(const int* __restrict__ ei, int E0, int ET,
                         const int* __restrict__ rowptr, int* __restrict__ cnt,
                         int* __restrict__ csr_src) {
  int e = blockIdx.x * blockDim.x + threadIdx.x;
  if (e >= ET) return;
  int s, d;
  if (e < E0) { s = ei[e]; d = ei[E0 + e]; }
  else        { s = e - E0; d = e - E0; }
  int pos = atomicAdd(&cnt[d], 1);
  csr_src[rowptr[d] + pos] = s;
}

// ---------------- fully-fused softmax + aggregate: ONE WAVE PER NODE ----------------
__global__ __launch_bounds__(256) void gat_fused_agg(
    const int* __restrict__ rowptr, const int* __restrict__ csr_src,
    const u16* __restrict__ Hb, const float* __restrict__ aSb,
    const float* __restrict__ aDb, const float* __restrict__ bias,
    u16* __restrict__ outB, float* __restrict__ outF, int N, int Hh) {
  const int wid = (int)((blockIdx.x * (blockDim.x >> 6)) + (threadIdx.x >> 6));
  const int lane = threadIdx.x & 63;
  if (wid >= N) return;
  const int beg = rowptr[wid];
  const int deg = rowptr[wid + 1] - beg;

  if (Hh == 4) {
    const int h = lane >> 4;        // softmax head AND gather head
    const int e16 = lane & 15;      // edge slot within chunk
    const int c0 = lane * 8;        // gather channels
    const int hbase = lane & 48;
    const float adh = aDb[(size_t)wid * 4 + h];
    float bv[8];
    *(float4*)&bv[0] = *(const float4*)&bias[c0];
    *(float4*)&bv[4] = *(const float4*)&bias[c0 + 4];
    float m = -1e30f, ssum = 0.f;
    float acc[8] = {};
    for (int c = 0; c < deg; c += 16) {
      const int ce = min(16, deg - c);
      int srcv = 0;
      float l = -1e30f;
      if (e16 < ce) {
        srcv = csr_src[beg + c + e16];
        l = lrelu(aSb[(size_t)srcv * 4 + h] + adh);
      }
      float cm = l;
#pragma unroll
      for (int o = 8; o; o >>= 1) cm = fmaxf(cm, __shfl_xor(cm, o));
      float pexp, cs;
      if (c == 0) {  // wave-uniform fast path: no rescale needed
        m = cm;
        pexp = expf(l - m);  // inactive lanes: exp(-inf)=0
        cs = pexp;
#pragma unroll
        for (int o = 8; o; o >>= 1) cs += __shfl_xor(cs, o);
        ssum = cs;
      } else {
        float newm = fmaxf(m, cm);
        float r = expf(m - newm);
        m = newm;
        pexp = expf(l - m);
        cs = pexp;
#pragma unroll
        for (int o = 8; o; o >>= 1) cs += __shfl_xor(cs, o);
        ssum = ssum * r + cs;
#pragma unroll
        for (int i = 0; i < 8; ++i) acc[i] *= r;
      }
      // gather: unroll 4 for memory-level parallelism
      int e = 0;
      for (; e + 4 <= ce; e += 4) {
        int se0 = __shfl(srcv, e + 0), se1 = __shfl(srcv, e + 1);
        int se2 = __shfl(srcv, e + 2), se3 = __shfl(srcv, e + 3);
        float w0 = __shfl(pexp, hbase | (e + 0)), w1 = __shfl(pexp, hbase | (e + 1));
        float w2 = __shfl(pexp, hbase | (e + 2)), w3 = __shfl(pexp, hbase | (e + 3));
        uint4 p0 = *(const uint4*)&Hb[(size_t)se0 * 512 + c0];
        uint4 p1 = *(const uint4*)&Hb[(size_t)se1 * 512 + c0];
        uint4 p2 = *(const uint4*)&Hb[(size_t)se2 * 512 + c0];
        uint4 p3 = *(const uint4*)&Hb[(size_t)se3 * 512 + c0];
#define ACC8(pv, wgt)                                             \
  acc[0] = fmaf(wgt, b2f((u16)(pv.x & 0xffff)), acc[0]);          \
  acc[1] = fmaf(wgt, b2f((u16)(pv.x >> 16)), acc[1]);             \
  acc[2] = fmaf(wgt, b2f((u16)(pv.y & 0xffff)), acc[2]);          \
  acc[3] = fmaf(wgt, b2f((u16)(pv.y >> 16)), acc[3]);             \
  acc[4] = fmaf(wgt, b2f((u16)(pv.z & 0xffff)), acc[4]);          \
  acc[5] = fmaf(wgt, b2f((u16)(pv.z >> 16)), acc[5]);             \
  acc[6] = fmaf(wgt, b2f((u16)(pv.w & 0xffff)), acc[6]);          \
  acc[7] = fmaf(wgt, b2f((u16)(pv.w >> 16)), acc[7]);
        ACC8(p0, w0)
        ACC8(p1, w1)
        ACC8(p2, w2)
        ACC8(p3, w3)
      }
      for (; e < ce; ++e) {
        int se = __shfl(srcv, e);
        float wgt = __shfl(pexp, hbase | e);
        uint4 pv = *(const uint4*)&Hb[(size_t)se * 512 + c0];
        ACC8(pv, wgt)
      }
    }
    const float inv = 1.f / ssum;
    u16 packed[8];
#pragma unroll
    for (int i = 0; i < 8; ++i) {
      float v = fmaf(acc[i], inv, bv[i]);
      v = v > 0.f ? v : expm1f(v);
      acc[i] = v;
      packed[i] = f2b(v);
    }
    if (outB) *(uint4*)&outB[(size_t)wid * 512 + c0] = *(const uint4*)packed;
    if (outF) {
      *(float4*)&outF[(size_t)wid * 512 + c0] = make_float4(acc[0], acc[1], acc[2], acc[3]);
      *(float4*)&outF[(size_t)wid * 512 + c0 + 4] =
          make_float4(acc[4], acc[5], acc[6], acc[7]);
    }
  } else {
    const int c0 = lane * 2;
    const float adh = aDb[wid];
    const float bv0 = bias[c0], bv1 = bias[c0 + 1];
    float m = -1e30f, ssum = 0.f;
    float a0 = 0.f, a1 = 0.f;
    for (int c = 0; c < deg; c += 64) {
      const int ce = min(64, deg - c);
      int srcv = 0;
      float l = -1e30f;
      if (lane < ce) {
        srcv = csr_src[beg + c + lane];
        l = lrelu(aSb[srcv] + adh);
      }
      float cm = l;
#pragma unroll
      for (int o = 32; o; o >>= 1) cm = fmaxf(cm, __shfl_xor(cm, o));
      float pexp, cs;
      if (c == 0) {
        m = cm;
        pexp = expf(l - m);
        cs = pexp;
#pragma unroll
        for (int o = 32; o; o >>= 1) cs += __shfl_xor(cs, o);
        ssum = cs;
      } else {
        float newm = fmaxf(m, cm);
        float r = expf(m - newm);
        m = newm;
        pexp = expf(l - m);
        cs = pexp;
#pragma unroll
        for (int o = 32; o; o >>= 1) cs += __shfl_xor(cs, o);
        ssum = ssum * r + cs;
        a0 *= r;
        a1 *= r;
      }
      int e = 0;
      for (; e + 4 <= ce; e += 4) {
        int se0 = __shfl(srcv, e + 0), se1 = __shfl(srcv, e + 1);
        int se2 = __shfl(srcv, e + 2), se3 = __shfl(srcv, e + 3);
        float w0 = __shfl(pexp, e + 0), w1 = __shfl(pexp, e + 1);
        float w2 = __shfl(pexp, e + 2), w3 = __shfl(pexp, e + 3);
        u32 p0 = *(const u32*)&Hb[(size_t)se0 * 128 + c0];
        u32 p1 = *(const u32*)&Hb[(size_t)se1 * 128 + c0];
        u32 p2 = *(const u32*)&Hb[(size_t)se2 * 128 + c0];
        u32 p3 = *(const u32*)&Hb[(size_t)se3 * 128 + c0];
        a0 = fmaf(w0, b2f((u16)(p0 & 0xffff)), a0);
        a1 = fmaf(w0, b2f((u16)(p0 >> 16)), a1);
        a0 = fmaf(w1, b2f((u16)(p1 & 0xffff)), a0);
        a1 = fmaf(w1, b2f((u16)(p1 >> 16)), a1);
        a0 = fmaf(w2, b2f((u16)(p2 & 0xffff)), a0);
        a1 = fmaf(w2, b2f((u16)(p2 >> 16)), a1);
        a0 = fmaf(w3, b2f((u16)(p3 & 0xffff)), a0);
        a1 = fmaf(w3, b2f((u16)(p3 >> 16)), a1);
      }
      for (; e < ce; ++e) {
        int se = __shfl(srcv, e);
        float wgt = __shfl(pexp, e);
        u32 pv = *(const u32*)&Hb[(size_t)se * 128 + c0];
        a0 = fmaf(wgt, b2f((u16)(pv & 0xffff)), a0);
        a1 = fmaf(wgt, b2f((u16)(pv >> 16)), a1);
      }
    }
    const float inv = 1.f / ssum;
    float v0 = fmaf(a0, inv, bv0), v1 = fmaf(a1, inv, bv1);
    v0 = v0 > 0.f ? v0 : expm1f(v0);
    v1 = v1 > 0.f ? v1 : expm1f(v1);
    if (outB) {
      u16 pk[2] = {f2b(v0), f2b(v1)};
      *(u32*)&outB[(size_t)wid * 128 + c0] = *(const u32*)pk;
    }
    if (outF) *(float2*)&outF[(size_t)wid * 128 + c0] = make_float2(v0, v1);
  }
}

// ---------------- fused FC head: (X@fc1w + b1).relu() @ fc2w + b2 -> sigmoid ----------------
__global__ __launch_bounds__(256) void fc_head(const float* __restrict__ A,
                                               const float* __restrict__ B,
                                               const float* __restrict__ bias,
                                               const float* __restrict__ w2,
                                               const float* __restrict__ b2,
                                               float* __restrict__ out, int M) {
  __shared__ float As[16][64];
  __shared__ float Bs[16][64];
  __shared__ float sP[64][17];
  const int tid = threadIdx.x;
  const int tx = tid & 15, ty = tid >> 4;
  const int mBase = blockIdx.y * 64;
  const int aRow = tid >> 2;
  const int aK = (tid & 3) << 2;
  const int bC = tid & 63;
  const int bR0 = tid >> 6;
  const int K = 128, N = 64;
  float acc[4][4] = {};
  for (int k0 = 0; k0 < K; k0 += 16) {
    float4 av = make_float4(0.f, 0.f, 0.f, 0.f);
    int gr = mBase + aRow;
    if (gr < M) av = *(const float4*)&A[(size_t)gr * K + k0 + aK];
    As[aK + 0][aRow] = av.x;
    As[aK + 1][aRow] = av.y;
    As[aK + 2][aRow] = av.z;
    As[aK + 3][aRow] = av.w;
#pragma unroll
    for (int i = 0; i < 4; ++i) {
      int r = bR0 + i * 4;
      Bs[r][bC] = B[(size_t)(k0 + r) * N + bC];
    }
    __syncthreads();
#pragma unroll
    for (int k = 0; k < 16; ++k) {
      float4 a = *(const float4*)&As[k][ty * 4];
      float4 b = *(const float4*)&Bs[k][tx * 4];
      float ar[4] = {a.x, a.y, a.z, a.w};
      float br[4] = {b.x, b.y, b.z, b.w};
#pragma unroll
      for (int i = 0; i < 4; ++i)
#pragma unroll
        for (int j = 0; j < 4; ++j) acc[i][j] = fmaf(ar[i], br[j], acc[i][j]);
    }
    __syncthreads();
  }
  float4 bv = *(const float4*)&bias[tx * 4];
  float4 wv = *(const float4*)&w2[tx * 4];
#pragma unroll
  for (int i = 0; i < 4; ++i) {
    float p = 0.f;
    p = fmaf(fmaxf(acc[i][0] + bv.x, 0.f), wv.x, p);
    p = fmaf(fmaxf(acc[i][1] + bv.y, 0.f), wv.y, p);
    p = fmaf(fmaxf(acc[i][2] + bv.z, 0.f), wv.z, p);
    p = fmaf(fmaxf(acc[i][3] + bv.w, 0.f), wv.w, p);
    sP[ty * 4 + i][tx] = p;
  }
  __syncthreads();
  if (tid < 64) {
    int row = mBase + tid;
    if (row < M) {
      float s = 0.f;
#pragma unroll
      for (int t = 0; t < 16; ++t) s += sP[tid][t];
      out[row] = 1.f / (1.f + expf(-(s + b2[0])));
    }
  }
}

// ---------------- launch ----------------
extern "C" void kernel_launch(void* const* d_in, const int* in_sizes, int n_in,
                              void* d_out, int out_size, void* d_ws, size_t ws_size,
                              hipStream_t stream) {
  const float* x    = (const float*)d_in[0];
  const int*   ei   = (const int*)d_in[1];
  const float* W1   = (const float*)d_in[2];
  const float* as1  = (const float*)d_in[3];
  const float* ad1  = (const float*)d_in[4];
  const float* b1   = (const float*)d_in[5];
  const float* W2   = (const float*)d_in[6];
  const float* as2  = (const float*)d_in[7];
  const float* ad2  = (const float*)d_in[8];
  const float* b2   = (const float*)d_in[9];
  const float* W3   = (const float*)d_in[10];
  const float* as3  = (const float*)d_in[11];
  const float* ad3  = (const float*)d_in[12];
  const float* b3   = (const float*)d_in[13];
  const float* fc1w = (const float*)d_in[14];
  const float* fc1b = (const float*)d_in[15];
  const float* fc2w = (const float*)d_in[16];
  const float* fc2b = (const float*)d_in[17];
  float* out = (float*)d_out;

  const int N  = in_sizes[0] / 64;  // 50000
  const int E0 = in_sizes[1] / 2;   // 400000
  const int ET = E0 + N;

  char* ws = (char*)d_ws;
  size_t off = 0;
  auto alloc = [&](size_t bytes) -> void* {
    void* p = ws + off;
    off += (bytes + 255) & ~(size_t)255;
    return p;
  };
  u16*   bufXb   = (u16*)alloc((size_t)N * 512 * 2);
  u16*   bufHb   = (u16*)alloc((size_t)N * 512 * 2);
  float* bufF    = (float*)alloc((size_t)N * 128 * 4);
  float* aS      = (float*)alloc((size_t)N * 4 * 4);
  float* aD      = (float*)alloc((size_t)N * 4 * 4);
  u16*   Wt1     = (u16*)alloc((size_t)512 * 64 * 2);
  u16*   Wt2     = (u16*)alloc((size_t)512 * 512 * 2);
  u16*   Wt3     = (u16*)alloc((size_t)128 * 512 * 2);
  int*   degcnt  = (int*)alloc((size_t)2 * N * 4);   // deg | cnt contiguous
  int*   deg     = degcnt;
  int*   cnt     = degcnt + N;
  int*   incl    = (int*)alloc((size_t)N * 4);
  int*   rowptr  = (int*)alloc((size_t)(N + 1) * 4);
  int*   bsums   = (int*)alloc(256 * 4);
  int*   csr_src = (int*)alloc((size_t)ET * 4);
  (void)ws_size; (void)n_in; (void)out_size;

  // ---- prep: zero deg/cnt, then fused casts + degree count ----
  hipMemsetAsync(degcnt, 0, (size_t)2 * N * 4, stream);
  const int NX = N * 64;
  const int prepTotal = NX + 64 * 512 + 512 * 512 + 512 * 128 + ET;
  hipLaunchKernelGGL(fused_prep, dim3((prepTotal + 255) / 256), dim3(256), 0, stream, x,
                     bufXb, NX, W1, Wt1, W2, Wt2, W3, Wt3, ei, E0, ET, deg);

  // ---- CSR scan + fill ----
  int nb = (N + 2047) / 2048;
  hipLaunchKernelGGL(scan_chunk, dim3(nb), dim3(256), 0, stream, deg, incl, bsums, N);
  hipLaunchKernelGGL(scan_final, dim3((N + 255) / 256), dim3(256), 0, stream, incl, bsums,
                     rowptr, N, nb);
  int eb = (ET + 255) / 256;
  hipLaunchKernelGGL(csr_fill, dim3(eb), dim3(256), 0, stream, ei, E0, ET, rowptr, cnt,
                     csr_src);

  const int gy = (N + 127) / 128;
  auto gat_layer = [&](int K, const u16* Wt, const float* a_s, const float* a_d,
                       const float* bias, int Hh, u16* aggB, float* aggF) {
    const int HC = Hh * 128;
    hipLaunchKernelGGL(gemm_bf16_gat, dim3(HC / 128, gy), dim3(256), 0, stream, bufXb, Wt,
                       bufHb, a_s, a_d, aS, aD, N, HC, K, Hh);
    hipLaunchKernelGGL(gat_fused_agg, dim3((N + 3) / 4), dim3(256), 0, stream, rowptr,
                       csr_src, bufHb, aS, aD, bias, aggB, aggF, N, Hh);
  };

  gat_layer(64,  Wt1, as1, ad1, b1, 4, bufXb, nullptr);
  gat_layer(512, Wt2, as2, ad2, b2, 4, bufXb, nullptr);
  gat_layer(512, Wt3, as3, ad3, b3, 1, nullptr, bufF);

  hipLaunchKernelGGL(fc_head, dim3(1, (N + 63) / 64), dim3(256), 0, stream, bufF, fc1w,
                     fc1b, fc2w, fc2b, out, N);
}